// Round 1
// baseline (524.265 us; speedup 1.0000x reference)
//
#include <hip/hip_runtime.h>
#include <math.h>

#define NUM_H 8
#define HD 32
#define DD 256

// ---------------- edge bias: last-write-wins scatter (numpy semantics) -----
__global__ void sel_init_kernel(int* __restrict__ sel, int N) {
  int t = blockIdx.x * 256 + threadIdx.x;
  if (t < N) sel[t] = -1;
}

__global__ void sel_scatter_kernel(const int* __restrict__ tgt, int* __restrict__ sel, int E) {
  int e = blockIdx.x * 256 + threadIdx.x;
  if (e < E) atomicMax(&sel[tgt[e]], e);   // max e == last occurrence wins
}

__global__ void bias_build_kernel(const int* __restrict__ sel, const float* __restrict__ ea,
                                  const float* __restrict__ We, const float* __restrict__ be,
                                  float* __restrict__ bias, int N) {
  int t = blockIdx.x * 256 + threadIdx.x;
  if (t >= N) return;
  int e = sel[t];
  bool has = (e >= 0);
  float a0 = 0.f, a1 = 0.f, a2 = 0.f;
  if (has) {
    a0 = ea[3 * (size_t)e];
    a1 = ea[3 * (size_t)e + 1];
    a2 = ea[3 * (size_t)e + 2];
  }
#pragma unroll
  for (int h = 0; h < NUM_H; ++h) {
    float v = has ? (a0 * We[h] + a1 * We[NUM_H + h] + a2 * We[2 * NUM_H + h] + be[h]) : 0.f;
    bias[(size_t)h * N + t] = v;   // [H][N] layout
  }
}

// ---------------- fp32 projection GEMM: Y = X(N,256) @ W(256,256) + b ------
// 16 rows/block, 256 threads. Thread tile: 4 rows x 4 cols.
// HEADLAYOUT=1 scatters into per-head [h][n][32] layout.
template <int HEADLAYOUT>
__global__ __launch_bounds__(256) void proj_kernel(const float* __restrict__ X,
                                                   const float* __restrict__ W,
                                                   const float* __restrict__ b,
                                                   float* __restrict__ Y, int N) {
  __shared__ float xs[16][DD];
  const int tid = threadIdx.x;
  const int row0 = blockIdx.x * 16;
#pragma unroll
  for (int p = 0; p < 4; ++p) {
    int ft = p * 256 + tid;            // 1024 float4 units
    int r = ft >> 6, c4 = ft & 63;
    float4 v = *reinterpret_cast<const float4*>(X + (size_t)(row0 + r) * DD + c4 * 4);
    *reinterpret_cast<float4*>(&xs[r][c4 * 4]) = v;
  }
  __syncthreads();
  const int c = (tid & 63) * 4;        // 4 consecutive output cols (stay in one head)
  const int r0 = (tid >> 6) * 4;       // 4 rows; whole wave shares r0 -> LDS broadcast
  float4 acc0 = make_float4(0, 0, 0, 0), acc1 = acc0, acc2 = acc0, acc3 = acc0;
  for (int k = 0; k < DD; k += 4) {
    float4 x0 = *reinterpret_cast<const float4*>(&xs[r0 + 0][k]);
    float4 x1 = *reinterpret_cast<const float4*>(&xs[r0 + 1][k]);
    float4 x2 = *reinterpret_cast<const float4*>(&xs[r0 + 2][k]);
    float4 x3 = *reinterpret_cast<const float4*>(&xs[r0 + 3][k]);
#pragma unroll
    for (int kk = 0; kk < 4; ++kk) {
      float4 w = *reinterpret_cast<const float4*>(W + (size_t)(k + kk) * DD + c);
      float a0 = kk == 0 ? x0.x : kk == 1 ? x0.y : kk == 2 ? x0.z : x0.w;
      float a1 = kk == 0 ? x1.x : kk == 1 ? x1.y : kk == 2 ? x1.z : x1.w;
      float a2 = kk == 0 ? x2.x : kk == 1 ? x2.y : kk == 2 ? x2.z : x2.w;
      float a3 = kk == 0 ? x3.x : kk == 1 ? x3.y : kk == 2 ? x3.z : x3.w;
      acc0.x += a0 * w.x; acc0.y += a0 * w.y; acc0.z += a0 * w.z; acc0.w += a0 * w.w;
      acc1.x += a1 * w.x; acc1.y += a1 * w.y; acc1.z += a1 * w.z; acc1.w += a1 * w.w;
      acc2.x += a2 * w.x; acc2.y += a2 * w.y; acc2.z += a2 * w.z; acc2.w += a2 * w.w;
      acc3.x += a3 * w.x; acc3.y += a3 * w.y; acc3.z += a3 * w.z; acc3.w += a3 * w.w;
    }
  }
  float4 bb = *reinterpret_cast<const float4*>(b + c);
  float4 accs[4] = {acc0, acc1, acc2, acc3};
#pragma unroll
  for (int r = 0; r < 4; ++r) {
    float4 o;
    o.x = accs[r].x + bb.x; o.y = accs[r].y + bb.y;
    o.z = accs[r].z + bb.z; o.w = accs[r].w + bb.w;
    int row = row0 + r0 + r;
    if (HEADLAYOUT) {
      int hh = c >> 5, d = c & 31;
      *reinterpret_cast<float4*>(Y + ((size_t)hh * N + row) * HD + d) = o;
    } else {
      *reinterpret_cast<float4*>(Y + (size_t)row * DD + c) = o;
    }
  }
}

// ---------------- flash attention, fp32 vector ------------------------------
// Per block: one head, 64 query rows. K-chunks of 64. 256 threads.
// Score phase: thread = (ty 0..15 -> 4 q rows) x (tx 0..15 -> 4 j cols).
// PV phase:    thread = same 4 q rows x 2 d cols (d = 2*tx).
// LDS tiles padded (stride 68 / 36) for conflict-free strided reads.
__global__ __launch_bounds__(256) void attn_kernel(const float* __restrict__ qh,
                                                   const float* __restrict__ kh,
                                                   const float* __restrict__ vh,
                                                   const float* __restrict__ biasg,
                                                   float* __restrict__ attn, int N) {
  __shared__ float Qt[32][68];   // transposed: [k][q]
  __shared__ float Kt[32][68];   // transposed: [k][j]
  __shared__ float Vt[64][36];   // [j][d]
  __shared__ float Ps[64][68];   // [j][q]
  __shared__ float bias_t[64];

  const int tid = threadIdx.x;
  const int h = blockIdx.y;
  const int q0 = blockIdx.x * 64;
  const int ty = tid >> 4;
  const int tx = tid & 15;

  // stage Q transposed (visible after the first loop-top barrier)
  const float* qbase = qh + ((size_t)h * N + q0) * HD;
#pragma unroll
  for (int p = 0; p < 2; ++p) {
    int ft = p * 256 + tid;
    int row = ft >> 3, k4 = ft & 7;
    float4 v = *reinterpret_cast<const float4*>(qbase + row * HD + k4 * 4);
    Qt[k4 * 4 + 0][row] = v.x;
    Qt[k4 * 4 + 1][row] = v.y;
    Qt[k4 * 4 + 2][row] = v.z;
    Qt[k4 * 4 + 3][row] = v.w;
  }

  float m_old[4], l[4];
  float2 acc[4];
#pragma unroll
  for (int i = 0; i < 4; ++i) { m_old[i] = -INFINITY; l[i] = 0.f; acc[i].x = 0.f; acc[i].y = 0.f; }

  const float* kbase = kh + (size_t)h * N * HD;
  const float* vbase = vh + (size_t)h * N * HD;
  const float* bbase = biasg + (size_t)h * N;

  for (int j0 = 0; j0 < N; j0 += 64) {
    __syncthreads();   // prev PV done (and, first iter, Q staging done)
#pragma unroll
    for (int p = 0; p < 2; ++p) {
      int ft = p * 256 + tid;
      int row = ft >> 3, k4 = ft & 7;
      float4 kv4 = *reinterpret_cast<const float4*>(kbase + (size_t)(j0 + row) * HD + k4 * 4);
      Kt[k4 * 4 + 0][row] = kv4.x;
      Kt[k4 * 4 + 1][row] = kv4.y;
      Kt[k4 * 4 + 2][row] = kv4.z;
      Kt[k4 * 4 + 3][row] = kv4.w;
      float4 vv4 = *reinterpret_cast<const float4*>(vbase + (size_t)(j0 + row) * HD + k4 * 4);
      *reinterpret_cast<float4*>(&Vt[row][k4 * 4]) = vv4;
    }
    if (tid < 64) bias_t[tid] = bbase[j0 + tid];
    __syncthreads();

    // ---- scores: 4q x 4j per thread
    float s[4][4];
#pragma unroll
    for (int a = 0; a < 4; ++a)
#pragma unroll
      for (int bj = 0; bj < 4; ++bj) s[a][bj] = 0.f;
#pragma unroll 8
    for (int k = 0; k < 32; ++k) {
      float4 qv = *reinterpret_cast<const float4*>(&Qt[k][ty * 4]);
      float4 kv = *reinterpret_cast<const float4*>(&Kt[k][tx * 4]);
      const float qa[4] = {qv.x, qv.y, qv.z, qv.w};
      const float ka[4] = {kv.x, kv.y, kv.z, kv.w};
#pragma unroll
      for (int a = 0; a < 4; ++a)
#pragma unroll
        for (int bj = 0; bj < 4; ++bj) s[a][bj] += qa[a] * ka[bj];
    }
    const float scl = 0.17677669529663687f;  // 1/sqrt(32)
    float bcol[4];
#pragma unroll
    for (int bj = 0; bj < 4; ++bj) bcol[bj] = bias_t[tx * 4 + bj];

    float mloc[4];
#pragma unroll
    for (int a = 0; a < 4; ++a) {
      float mm = -INFINITY;
#pragma unroll
      for (int bj = 0; bj < 4; ++bj) {
        s[a][bj] = s[a][bj] * scl + bcol[bj];
        mm = fmaxf(mm, s[a][bj]);
      }
      mloc[a] = mm;
    }
    // row reduce over the 16 tx lanes (consecutive lanes share ty)
#pragma unroll
    for (int mask = 1; mask <= 8; mask <<= 1) {
#pragma unroll
      for (int a = 0; a < 4; ++a) mloc[a] = fmaxf(mloc[a], __shfl_xor(mloc[a], mask));
    }
    float pp[4][4], sf[4], rs[4];
#pragma unroll
    for (int a = 0; a < 4; ++a) {
      float mn = fmaxf(m_old[a], mloc[a]);
      sf[a] = __expf(m_old[a] - mn);
      m_old[a] = mn;
      float r = 0.f;
#pragma unroll
      for (int bj = 0; bj < 4; ++bj) {
        pp[a][bj] = __expf(s[a][bj] - mn);
        r += pp[a][bj];
      }
      rs[a] = r;
    }
#pragma unroll
    for (int mask = 1; mask <= 8; mask <<= 1) {
#pragma unroll
      for (int a = 0; a < 4; ++a) rs[a] += __shfl_xor(rs[a], mask);
    }
#pragma unroll
    for (int a = 0; a < 4; ++a) {
      l[a] = l[a] * sf[a] + rs[a];
      acc[a].x *= sf[a];
      acc[a].y *= sf[a];
    }
    // P -> LDS as [j][q]
#pragma unroll
    for (int bj = 0; bj < 4; ++bj) {
      float4 w;
      w.x = pp[0][bj]; w.y = pp[1][bj]; w.z = pp[2][bj]; w.w = pp[3][bj];
      *reinterpret_cast<float4*>(&Ps[tx * 4 + bj][ty * 4]) = w;
    }
    __syncthreads();

    // ---- PV: 4q x 2d per thread over 64 j
#pragma unroll 4
    for (int j = 0; j < 64; ++j) {
      float4 pv = *reinterpret_cast<const float4*>(&Ps[j][ty * 4]);
      float2 vv = *reinterpret_cast<const float2*>(&Vt[j][tx * 2]);
      acc[0].x += pv.x * vv.x; acc[0].y += pv.x * vv.y;
      acc[1].x += pv.y * vv.x; acc[1].y += pv.y * vv.y;
      acc[2].x += pv.z * vv.x; acc[2].y += pv.z * vv.y;
      acc[3].x += pv.w * vv.x; acc[3].y += pv.w * vv.y;
    }
  }

#pragma unroll
  for (int a = 0; a < 4; ++a) {
    float inv = 1.f / l[a];
    int row = q0 + ty * 4 + a;
    float2 o;
    o.x = acc[a].x * inv;
    o.y = acc[a].y * inv;
    // [N][256] layout: col = h*32 + d
    *reinterpret_cast<float2*>(attn + (size_t)row * DD + h * HD + tx * 2) = o;
  }
}

// ---------------------------------------------------------------------------
extern "C" void kernel_launch(void* const* d_in, const int* in_sizes, int n_in,
                              void* d_out, int out_size, void* d_ws, size_t ws_size,
                              hipStream_t stream) {
  const float* x  = (const float*)d_in[0];
  const int* eidx = (const int*)d_in[1];
  const float* ea = (const float*)d_in[2];
  const float* Wq = (const float*)d_in[3];
  const float* bq = (const float*)d_in[4];
  const float* Wk = (const float*)d_in[5];
  const float* bk = (const float*)d_in[6];
  const float* Wv = (const float*)d_in[7];
  const float* bv = (const float*)d_in[8];
  const float* Wo = (const float*)d_in[9];
  const float* bo = (const float*)d_in[10];
  const float* We = (const float*)d_in[11];
  const float* be = (const float*)d_in[12];
  float* out = (float*)d_out;

  const int N = in_sizes[0] / DD;     // B=1
  const int E = in_sizes[1] / 2;
  const int* tgt = eidx + E;          // edge_index[1]

  // workspace layout (floats)
  float* qh   = (float*)d_ws;                     // [H][N][32]
  float* khp  = qh   + (size_t)N * DD;            // [H][N][32]
  float* vhp  = khp  + (size_t)N * DD;            // [H][N][32]
  float* attn = vhp  + (size_t)N * DD;            // [N][256]
  float* bias = attn + (size_t)N * DD;            // [H][N]
  int*   sel  = (int*)(bias + (size_t)NUM_H * N); // [N]

  sel_init_kernel<<<(N + 255) / 256, 256, 0, stream>>>(sel, N);
  sel_scatter_kernel<<<(E + 255) / 256, 256, 0, stream>>>(tgt, sel, E);
  bias_build_kernel<<<(N + 255) / 256, 256, 0, stream>>>(sel, ea, We, be, bias, N);

  proj_kernel<1><<<N / 16, 256, 0, stream>>>(x, Wq, bq, qh, N);
  proj_kernel<1><<<N / 16, 256, 0, stream>>>(x, Wk, bk, khp, N);
  proj_kernel<1><<<N / 16, 256, 0, stream>>>(x, Wv, bv, vhp, N);

  dim3 ag(N / 64, NUM_H);
  attn_kernel<<<ag, 256, 0, stream>>>(qh, khp, vhp, bias, attn, N);

  proj_kernel<0><<<N / 16, 256, 0, stream>>>(attn, Wo, bo, out, N);
}

// Round 2
// 187.881 us; speedup vs baseline: 2.7904x; 2.7904x over previous
//
#include <hip/hip_runtime.h>
#include <math.h>

#define NUM_H 8
#define HD 32
#define DD 256

typedef __attribute__((ext_vector_type(8))) short bf16x8;
typedef __attribute__((ext_vector_type(4))) float f32x4;
typedef __attribute__((ext_vector_type(4))) unsigned short u16x4;

__device__ __forceinline__ unsigned short f2b(float f) {
  unsigned u = __builtin_bit_cast(unsigned, f);
  u += 0x7FFFu + ((u >> 16) & 1u);   // RNE
  return (unsigned short)(u >> 16);
}

// ---------------- edge bias: last-write-wins scatter (numpy semantics) -----
__global__ void sel_init_kernel(int* __restrict__ sel, int N) {
  int t = blockIdx.x * 256 + threadIdx.x;
  if (t < N) sel[t] = -1;
}

__global__ void sel_scatter_kernel(const int* __restrict__ tgt, int* __restrict__ sel, int E) {
  int e = blockIdx.x * 256 + threadIdx.x;
  if (e < E) atomicMax(&sel[tgt[e]], e);   // max e == last occurrence wins
}

__global__ void bias_build_kernel(const int* __restrict__ sel, const float* __restrict__ ea,
                                  const float* __restrict__ We, const float* __restrict__ be,
                                  float* __restrict__ bias, int N) {
  int t = blockIdx.x * 256 + threadIdx.x;
  if (t >= N) return;
  int e = sel[t];
  bool has = (e >= 0);
  float a0 = 0.f, a1 = 0.f, a2 = 0.f;
  if (has) {
    a0 = ea[3 * (size_t)e];
    a1 = ea[3 * (size_t)e + 1];
    a2 = ea[3 * (size_t)e + 2];
  }
#pragma unroll
  for (int h = 0; h < NUM_H; ++h) {
    float v = has ? (a0 * We[h] + a1 * We[NUM_H + h] + a2 * We[2 * NUM_H + h] + be[h]) : 0.f;
    bias[(size_t)h * N + t] = v;   // [H][N]
  }
}

// ---------------- fp32 -> bf16 converts ------------------------------------
__global__ void cvt_x_kernel(const float* __restrict__ x, unsigned short* __restrict__ xb) {
  int i = blockIdx.x * 256 + threadIdx.x;   // 4 elems per thread
  const float4 v = *reinterpret_cast<const float4*>(x + (size_t)i * 4);
  u16x4 o;
  o[0] = f2b(v.x); o[1] = f2b(v.y); o[2] = f2b(v.z); o[3] = f2b(v.w);
  *reinterpret_cast<u16x4*>(xb + (size_t)i * 4) = o;
}

// WT[c][k] = bf16(W[k][c])  (256x256), LDS tile transpose
__global__ void cvt_wt_kernel(const float* __restrict__ W, unsigned short* __restrict__ WT) {
  __shared__ float t[32][33];
  const int bx = blockIdx.x, by = blockIdx.y;
  const int lx = threadIdx.x & 31, ly = threadIdx.x >> 5;   // 256 thr: ly 0..7
#pragma unroll
  for (int r = 0; r < 32; r += 8)
    t[r + ly][lx] = W[(size_t)(bx * 32 + r + ly) * DD + by * 32 + lx];
  __syncthreads();
#pragma unroll
  for (int r = 0; r < 32; r += 8)
    WT[(size_t)(by * 32 + r + ly) * DD + bx * 32 + lx] = f2b(t[lx][r + ly]);
}

// ---------------- MFMA projection: Y = Xb(N,256) @ W + bias ----------------
// wave tile 16n x 32c, K-loop 8 x mfma_16x16x32. All operands from global (L2).
// MODE 0: bf16 [N][256]; MODE 1: bf16 transposed [256][N]; MODE 2: f32 [N][256]
template <int MODE>
__global__ __launch_bounds__(256) void proj_mfma(const unsigned short* __restrict__ Xb,
                                                 const unsigned short* __restrict__ WT,
                                                 const float* __restrict__ bias,
                                                 void* __restrict__ Y, int N) {
  const int w = threadIdx.x >> 6, l = threadIdx.x & 63;
  const int lr = l & 15, lg = l >> 4;
  const int n0 = (blockIdx.x * 4 + w) * 16;
  const int c0 = blockIdx.y * 32;
  const f32x4 zero4 = {0.f, 0.f, 0.f, 0.f};
  f32x4 acc0 = zero4, acc1 = zero4;
  const unsigned short* ap  = Xb + (size_t)(n0 + lr) * DD + lg * 8;
  const unsigned short* bp0 = WT + (size_t)(c0 + lr) * DD + lg * 8;
  const unsigned short* bp1 = bp0 + 16 * DD;
#pragma unroll
  for (int kk = 0; kk < 8; ++kk) {
    bf16x8 a  = *reinterpret_cast<const bf16x8*>(ap + kk * 32);
    bf16x8 b0 = *reinterpret_cast<const bf16x8*>(bp0 + kk * 32);
    bf16x8 b1 = *reinterpret_cast<const bf16x8*>(bp1 + kk * 32);
    acc0 = __builtin_amdgcn_mfma_f32_16x16x32_bf16(a, b0, acc0, 0, 0, 0);
    acc1 = __builtin_amdgcn_mfma_f32_16x16x32_bf16(a, b1, acc1, 0, 0, 0);
  }
  const float bc0 = bias[c0 + lr], bc1 = bias[c0 + 16 + lr];
  if (MODE == 0) {
    unsigned short* Yb = (unsigned short*)Y;
#pragma unroll
    for (int r = 0; r < 4; ++r) {
      Yb[(size_t)(n0 + lg * 4 + r) * DD + c0 + lr]      = f2b(acc0[r] + bc0);
      Yb[(size_t)(n0 + lg * 4 + r) * DD + c0 + 16 + lr] = f2b(acc1[r] + bc1);
    }
  } else if (MODE == 1) {
    unsigned short* Yb = (unsigned short*)Y;
    u16x4 o0, o1;
#pragma unroll
    for (int r = 0; r < 4; ++r) {
      o0[r] = f2b(acc0[r] + bc0);
      o1[r] = f2b(acc1[r] + bc1);
    }
    *reinterpret_cast<u16x4*>(Yb + (size_t)(c0 + lr) * N + n0 + lg * 4)      = o0;
    *reinterpret_cast<u16x4*>(Yb + (size_t)(c0 + 16 + lr) * N + n0 + lg * 4) = o1;
  } else {
    float* Yf = (float*)Y;
#pragma unroll
    for (int r = 0; r < 4; ++r) {
      Yf[(size_t)(n0 + lg * 4 + r) * DD + c0 + lr]      = acc0[r] + bc0;
      Yf[(size_t)(n0 + lg * 4 + r) * DD + c0 + 16 + lr] = acc1[r] + bc1;
    }
  }
}

// ---------------- flash attention, bf16 MFMA --------------------------------
// Block: 4 independent waves (no barriers). Wave: 16 q-rows of one head.
// Swapped QK^T: S^T = mfma(K_frag, Q_frag) -> lane owns q = lane&15.
// j-tiles of 64: 4 QK MFMA + reg-local softmax (2 shfl_xor) + P->LDS(bf16)
// -> 4 PV MFMA with V^T operand streamed from global.
__global__ __launch_bounds__(256) void attn_mfma(const unsigned short* __restrict__ qb,
                                                 const unsigned short* __restrict__ kb,
                                                 const unsigned short* __restrict__ vT,
                                                 const float* __restrict__ biasg,
                                                 unsigned short* __restrict__ ob, int N) {
  __shared__ unsigned short P_lds[4][16 * 72];   // per-wave [16 q][64 j], stride 72 (16B-aligned reads)
  const int w = threadIdx.x >> 6, l = threadIdx.x & 63;
  const int lr = l & 15, lg = l >> 4;
  const int h = blockIdx.y;
  const int q0 = blockIdx.x * 64 + w * 16;
  const int hk = h * HD;
  const float scl = 0.17677669529663687f;   // 1/sqrt(32)

  const bf16x8 qf = *reinterpret_cast<const bf16x8*>(qb + (size_t)(q0 + lr) * DD + hk + lg * 8);

  const unsigned short* kbase = kb + hk + lg * 8;
  const unsigned short* vbase = vT + (size_t)hk * N + lg * 8;
  const float* bb = biasg + (size_t)h * N;
  unsigned short* Pw = P_lds[w];
  const int pbase = lr * 72;

  float m_old = -INFINITY, lsum = 0.f;
  const f32x4 zero4 = {0.f, 0.f, 0.f, 0.f};
  f32x4 oacc0 = zero4, oacc1 = zero4;

  // register double-buffered K-frags
  bf16x8 kf0 = *reinterpret_cast<const bf16x8*>(kbase + (size_t)(lr) * DD);
  bf16x8 kf1 = *reinterpret_cast<const bf16x8*>(kbase + (size_t)(16 + lr) * DD);
  bf16x8 kf2 = *reinterpret_cast<const bf16x8*>(kbase + (size_t)(32 + lr) * DD);
  bf16x8 kf3 = *reinterpret_cast<const bf16x8*>(kbase + (size_t)(48 + lr) * DD);

  for (int j0 = 0; j0 < N; j0 += 64) {
    // V loads for this tile (latency hides under QK + softmax)
    const unsigned short* vrow0 = vbase + (size_t)(lr) * N + j0;        // d-frag 0
    const unsigned short* vrow1 = vbase + (size_t)(16 + lr) * N + j0;   // d-frag 1
    const bf16x8 v00 = *reinterpret_cast<const bf16x8*>(vrow0);         // j-chunk 0
    const bf16x8 v10 = *reinterpret_cast<const bf16x8*>(vrow0 + 32);    // j-chunk 1
    const bf16x8 v01 = *reinterpret_cast<const bf16x8*>(vrow1);
    const bf16x8 v11 = *reinterpret_cast<const bf16x8*>(vrow1 + 32);

    // per-lane bias for its 16 j values: j = jf*16 + lg*4 + r
    f32x4 bias4[4];
#pragma unroll
    for (int jf = 0; jf < 4; ++jf)
      bias4[jf] = *reinterpret_cast<const f32x4*>(bb + j0 + jf * 16 + lg * 4);

    f32x4 s[4];
    s[0] = __builtin_amdgcn_mfma_f32_16x16x32_bf16(kf0, qf, zero4, 0, 0, 0);
    s[1] = __builtin_amdgcn_mfma_f32_16x16x32_bf16(kf1, qf, zero4, 0, 0, 0);
    s[2] = __builtin_amdgcn_mfma_f32_16x16x32_bf16(kf2, qf, zero4, 0, 0, 0);
    s[3] = __builtin_amdgcn_mfma_f32_16x16x32_bf16(kf3, qf, zero4, 0, 0, 0);

    if (j0 + 64 < N) {   // prefetch next tile's K-frags
      kf0 = *reinterpret_cast<const bf16x8*>(kbase + (size_t)(j0 + 64 + lr) * DD);
      kf1 = *reinterpret_cast<const bf16x8*>(kbase + (size_t)(j0 + 80 + lr) * DD);
      kf2 = *reinterpret_cast<const bf16x8*>(kbase + (size_t)(j0 + 96 + lr) * DD);
      kf3 = *reinterpret_cast<const bf16x8*>(kbase + (size_t)(j0 + 112 + lr) * DD);
    }

    // scale + bias, local max over this lane's 16 j values
    float p[4][4];
    float mloc = -INFINITY;
#pragma unroll
    for (int jf = 0; jf < 4; ++jf)
#pragma unroll
      for (int r = 0; r < 4; ++r) {
        float t = s[jf][r] * scl + bias4[jf][r];
        p[jf][r] = t;
        mloc = fmaxf(mloc, t);
      }
    mloc = fmaxf(mloc, __shfl_xor(mloc, 16));
    mloc = fmaxf(mloc, __shfl_xor(mloc, 32));

    if (__any(mloc > m_old)) {   // exact defer: rescale only when max grows
      float m_new = fmaxf(m_old, mloc);
      float sf = __expf(m_old - m_new);
      m_old = m_new;
      lsum *= sf;
      float sf0 = __shfl(sf, lg * 4 + 0);
      float sf1 = __shfl(sf, lg * 4 + 1);
      float sf2 = __shfl(sf, lg * 4 + 2);
      float sf3 = __shfl(sf, lg * 4 + 3);
      oacc0[0] *= sf0; oacc0[1] *= sf1; oacc0[2] *= sf2; oacc0[3] *= sf3;
      oacc1[0] *= sf0; oacc1[1] *= sf1; oacc1[2] *= sf2; oacc1[3] *= sf3;
    }

    float rsum = 0.f;
#pragma unroll
    for (int jf = 0; jf < 4; ++jf) {
      u16x4 pk;
#pragma unroll
      for (int r = 0; r < 4; ++r) {
        float e = __expf(p[jf][r] - m_old);
        rsum += e;
        pk[r] = f2b(e);
      }
      // P[q=lr][j = jf*16 + lg*4 + r]
      *reinterpret_cast<u16x4*>(Pw + pbase + jf * 16 + lg * 4) = pk;
    }
    rsum += __shfl_xor(rsum, 16);
    rsum += __shfl_xor(rsum, 32);
    lsum += rsum;

    // PV: O[16q][32d] += P[16q][64j] * V[64j][32d]
    const bf16x8 pf0 = *reinterpret_cast<const bf16x8*>(Pw + pbase + lg * 8);
    const bf16x8 pf1 = *reinterpret_cast<const bf16x8*>(Pw + pbase + 32 + lg * 8);
    oacc0 = __builtin_amdgcn_mfma_f32_16x16x32_bf16(pf0, v00, oacc0, 0, 0, 0);
    oacc1 = __builtin_amdgcn_mfma_f32_16x16x32_bf16(pf0, v01, oacc1, 0, 0, 0);
    oacc0 = __builtin_amdgcn_mfma_f32_16x16x32_bf16(pf1, v10, oacc0, 0, 0, 0);
    oacc1 = __builtin_amdgcn_mfma_f32_16x16x32_bf16(pf1, v11, oacc1, 0, 0, 0);
  }

  const float invl = 1.f / lsum;   // stats live at q = lr
#pragma unroll
  for (int r = 0; r < 4; ++r) {
    float iv = __shfl(invl, lg * 4 + r);   // row q = lg*4 + r of the D layout
    ob[(size_t)(q0 + lg * 4 + r) * DD + hk + lr]      = f2b(oacc0[r] * iv);
    ob[(size_t)(q0 + lg * 4 + r) * DD + hk + 16 + lr] = f2b(oacc1[r] * iv);
  }
}

// ---------------------------------------------------------------------------
extern "C" void kernel_launch(void* const* d_in, const int* in_sizes, int n_in,
                              void* d_out, int out_size, void* d_ws, size_t ws_size,
                              hipStream_t stream) {
  const float* x  = (const float*)d_in[0];
  const int* eidx = (const int*)d_in[1];
  const float* ea = (const float*)d_in[2];
  const float* Wq = (const float*)d_in[3];
  const float* bq = (const float*)d_in[4];
  const float* Wk = (const float*)d_in[5];
  const float* bk = (const float*)d_in[6];
  const float* Wv = (const float*)d_in[7];
  const float* bv = (const float*)d_in[8];
  const float* Wo = (const float*)d_in[9];
  const float* bo = (const float*)d_in[10];
  const float* We = (const float*)d_in[11];
  const float* be = (const float*)d_in[12];
  float* out = (float*)d_out;

  const int N = in_sizes[0] / DD;   // B=1
  const int E = in_sizes[1] / 2;
  const int* tgt = eidx + E;        // edge_index[1]

  // workspace layout (all 16B-aligned sizes)
  unsigned short* xb  = (unsigned short*)d_ws;            // [N][256] bf16
  unsigned short* qbf = xb  + (size_t)N * DD;             // [N][256]
  unsigned short* kbf = qbf + (size_t)N * DD;             // [N][256]
  unsigned short* vT  = kbf + (size_t)N * DD;             // [256][N] transposed
  unsigned short* obf = vT  + (size_t)N * DD;             // [N][256]
  unsigned short* WTq = obf + (size_t)N * DD;             // [256][256] bf16 (W^T)
  unsigned short* WTk = WTq + DD * DD;
  unsigned short* WTv = WTk + DD * DD;
  unsigned short* WTo = WTv + DD * DD;
  float* bias = (float*)(WTo + DD * DD);                  // [H][N] f32
  int*   sel  = (int*)(bias + (size_t)NUM_H * N);         // [N]

  sel_init_kernel<<<(N + 255) / 256, 256, 0, stream>>>(sel, N);
  sel_scatter_kernel<<<(E + 255) / 256, 256, 0, stream>>>(tgt, sel, E);
  bias_build_kernel<<<(N + 255) / 256, 256, 0, stream>>>(sel, ea, We, be, bias, N);

  cvt_x_kernel<<<(N * DD) / 1024, 256, 0, stream>>>(x, xb);
  dim3 wg(8, 8);
  cvt_wt_kernel<<<wg, 256, 0, stream>>>(Wq, WTq);
  cvt_wt_kernel<<<wg, 256, 0, stream>>>(Wk, WTk);
  cvt_wt_kernel<<<wg, 256, 0, stream>>>(Wv, WTv);
  cvt_wt_kernel<<<wg, 256, 0, stream>>>(Wo, WTo);

  dim3 pg(N / 64, DD / 32);
  proj_mfma<0><<<pg, 256, 0, stream>>>(xb, WTq, bq, qbf, N);
  proj_mfma<0><<<pg, 256, 0, stream>>>(xb, WTk, bk, kbf, N);
  proj_mfma<1><<<pg, 256, 0, stream>>>(xb, WTv, bv, vT, N);

  dim3 ag(N / 64, NUM_H);
  attn_mfma<<<ag, 256, 0, stream>>>(qbf, kbf, vT, bias, obf, N);

  proj_mfma<2><<<pg, 256, 0, stream>>>(obf, WTo, bo, out, N);
}

// Round 4
// 185.147 us; speedup vs baseline: 2.8316x; 1.0148x over previous
//
#include <hip/hip_runtime.h>
#include <hip/hip_bf16.h>
#include <math.h>

#define NUM_H 8
#define HD 32
#define DD 256
#define NSPLIT 4

typedef __attribute__((ext_vector_type(8))) short bf16x8;
typedef __attribute__((ext_vector_type(4))) float f32x4;
typedef __attribute__((ext_vector_type(4))) unsigned short u16x4;

__device__ __forceinline__ unsigned short f2b(float f) {
  unsigned u = __builtin_bit_cast(unsigned, f);
  u += 0x7FFFu + ((u >> 16) & 1u);   // RNE
  return (unsigned short)(u >> 16);
}

__device__ __forceinline__ unsigned pack2(float a, float b) {
  float2 t; t.x = a; t.y = b;
  __hip_bfloat162 r = __float22bfloat162_rn(t);   // v_cvt_pk_bf16_f32
  unsigned u;
  __builtin_memcpy(&u, &r, sizeof(u));            // bit_cast rejected: not trivially copyable
  return u;
}

#define LOG2E 1.4426950408889634f

// ---------------- edge bias: last-write-wins scatter (numpy semantics) -----
__global__ void sel_init_kernel(int* __restrict__ sel, int N) {
  int t = blockIdx.x * 256 + threadIdx.x;
  if (t < N) sel[t] = -1;
}

__global__ void sel_scatter_kernel(const int* __restrict__ tgt, int* __restrict__ sel, int E) {
  int e = blockIdx.x * 256 + threadIdx.x;
  if (e < E) atomicMax(&sel[tgt[e]], e);   // max e == last occurrence wins
}

// stores bias * log2(e)  (softmax done in exp2 domain)
__global__ void bias_build_kernel(const int* __restrict__ sel, const float* __restrict__ ea,
                                  const float* __restrict__ We, const float* __restrict__ be,
                                  float* __restrict__ bias, int N) {
  int t = blockIdx.x * 256 + threadIdx.x;
  if (t >= N) return;
  int e = sel[t];
  bool has = (e >= 0);
  float a0 = 0.f, a1 = 0.f, a2 = 0.f;
  if (has) {
    a0 = ea[3 * (size_t)e];
    a1 = ea[3 * (size_t)e + 1];
    a2 = ea[3 * (size_t)e + 2];
  }
#pragma unroll
  for (int h = 0; h < NUM_H; ++h) {
    float v = has ? (a0 * We[h] + a1 * We[NUM_H + h] + a2 * We[2 * NUM_H + h] + be[h]) : 0.f;
    bias[(size_t)h * N + t] = v * LOG2E;   // [H][N]
  }
}

// ---------------- fp32 -> bf16 converts ------------------------------------
__global__ void cvt_x_kernel(const float* __restrict__ x, unsigned short* __restrict__ xb) {
  int i = blockIdx.x * 256 + threadIdx.x;   // 4 elems per thread
  const float4 v = *reinterpret_cast<const float4*>(x + (size_t)i * 4);
  uint2 o;
  o.x = pack2(v.x, v.y);
  o.y = pack2(v.z, v.w);
  *reinterpret_cast<uint2*>(xb + (size_t)i * 4) = o;
}

// WT[c][k] = bf16(W[k][c]) for 4 weights, LDS tile transpose. z picks the matrix.
__global__ void cvt_wt_all(const float* __restrict__ W0, const float* __restrict__ W1,
                           const float* __restrict__ W2, const float* __restrict__ W3,
                           unsigned short* __restrict__ T0, unsigned short* __restrict__ T1,
                           unsigned short* __restrict__ T2, unsigned short* __restrict__ T3) {
  __shared__ float t[32][33];
  const int z = blockIdx.z;
  const float* W = (z == 0) ? W0 : (z == 1) ? W1 : (z == 2) ? W2 : W3;
  unsigned short* WT = (z == 0) ? T0 : (z == 1) ? T1 : (z == 2) ? T2 : T3;
  const int bx = blockIdx.x, by = blockIdx.y;
  const int lx = threadIdx.x & 31, ly = threadIdx.x >> 5;   // 256 thr: ly 0..7
#pragma unroll
  for (int r = 0; r < 32; r += 8)
    t[r + ly][lx] = W[(size_t)(bx * 32 + r + ly) * DD + by * 32 + lx];
  __syncthreads();
#pragma unroll
  for (int r = 0; r < 32; r += 8)
    WT[(size_t)(by * 32 + r + ly) * DD + bx * 32 + lx] = f2b(t[lx][r + ly]);
}

// ---------------- MFMA projection core -------------------------------------
// wave tile 16n x 32c, K-loop 8 x mfma_16x16x32. Operands from global (L2).
__device__ __forceinline__ void proj_core(const unsigned short* __restrict__ Xb,
                                          const unsigned short* __restrict__ WT,
                                          int n0, int c0, int lr, int lg,
                                          f32x4& acc0, f32x4& acc1) {
  const f32x4 zero4 = {0.f, 0.f, 0.f, 0.f};
  acc0 = zero4; acc1 = zero4;
  const unsigned short* ap  = Xb + (size_t)(n0 + lr) * DD + lg * 8;
  const unsigned short* bp0 = WT + (size_t)(c0 + lr) * DD + lg * 8;
  const unsigned short* bp1 = bp0 + 16 * DD;
#pragma unroll
  for (int kk = 0; kk < 8; ++kk) {
    bf16x8 a  = *reinterpret_cast<const bf16x8*>(ap + kk * 32);
    bf16x8 b0 = *reinterpret_cast<const bf16x8*>(bp0 + kk * 32);
    bf16x8 b1 = *reinterpret_cast<const bf16x8*>(bp1 + kk * 32);
    acc0 = __builtin_amdgcn_mfma_f32_16x16x32_bf16(a, b0, acc0, 0, 0, 0);
    acc1 = __builtin_amdgcn_mfma_f32_16x16x32_bf16(a, b1, acc1, 0, 0, 0);
  }
}

// fused Q/K/V projection; z = 0:Q (bf16 [N][256]), 1:K (bf16 [N][256]),
// 2:V (bf16 transposed [256][N])
__global__ __launch_bounds__(256) void proj_qkv(const unsigned short* __restrict__ Xb,
                                                const unsigned short* __restrict__ WTq,
                                                const unsigned short* __restrict__ WTk,
                                                const unsigned short* __restrict__ WTv,
                                                const float* __restrict__ bq,
                                                const float* __restrict__ bk,
                                                const float* __restrict__ bv,
                                                unsigned short* __restrict__ qbf,
                                                unsigned short* __restrict__ kbf,
                                                unsigned short* __restrict__ vT, int N) {
  const int z = blockIdx.z;
  const unsigned short* WT = (z == 0) ? WTq : (z == 1) ? WTk : WTv;
  const float* bias = (z == 0) ? bq : (z == 1) ? bk : bv;
  const int w = threadIdx.x >> 6, l = threadIdx.x & 63;
  const int lr = l & 15, lg = l >> 4;
  const int n0 = (blockIdx.x * 4 + w) * 16;
  const int c0 = blockIdx.y * 32;
  f32x4 acc0, acc1;
  proj_core(Xb, WT, n0, c0, lr, lg, acc0, acc1);
  const float bc0 = bias[c0 + lr], bc1 = bias[c0 + 16 + lr];
  if (z < 2) {
    unsigned short* Yb = z ? kbf : qbf;
#pragma unroll
    for (int r = 0; r < 4; ++r) {
      Yb[(size_t)(n0 + lg * 4 + r) * DD + c0 + lr]      = f2b(acc0[r] + bc0);
      Yb[(size_t)(n0 + lg * 4 + r) * DD + c0 + 16 + lr] = f2b(acc1[r] + bc1);
    }
  } else {
    uint2 o0, o1;
    o0.x = pack2(acc0[0] + bc0, acc0[1] + bc0);
    o0.y = pack2(acc0[2] + bc0, acc0[3] + bc0);
    o1.x = pack2(acc1[0] + bc1, acc1[1] + bc1);
    o1.y = pack2(acc1[2] + bc1, acc1[3] + bc1);
    *reinterpret_cast<uint2*>(vT + (size_t)(c0 + lr) * N + n0 + lg * 4)      = o0;
    *reinterpret_cast<uint2*>(vT + (size_t)(c0 + 16 + lr) * N + n0 + lg * 4) = o1;
  }
}

// output projection: f32 out
__global__ __launch_bounds__(256) void proj_out(const unsigned short* __restrict__ Xb,
                                                const unsigned short* __restrict__ WT,
                                                const float* __restrict__ bias,
                                                float* __restrict__ Y, int N) {
  const int w = threadIdx.x >> 6, l = threadIdx.x & 63;
  const int lr = l & 15, lg = l >> 4;
  const int n0 = (blockIdx.x * 4 + w) * 16;
  const int c0 = blockIdx.y * 32;
  f32x4 acc0, acc1;
  proj_core(Xb, WT, n0, c0, lr, lg, acc0, acc1);
  const float bc0 = bias[c0 + lr], bc1 = bias[c0 + 16 + lr];
#pragma unroll
  for (int r = 0; r < 4; ++r) {
    Y[(size_t)(n0 + lg * 4 + r) * DD + c0 + lr]      = acc0[r] + bc0;
    Y[(size_t)(n0 + lg * 4 + r) * DD + c0 + 16 + lr] = acc1[r] + bc1;
  }
}

// ---------------- flash attention, bf16 MFMA, split-j ------------------------
// grid (N/64, H, NSPLIT). Block: 4 independent waves (no barriers).
// Wave: 16 q-rows of one head over j in [z*N/S, (z+1)*N/S).
// Swapped QK^T: S^T = mfma(K_frag, Q_frag) -> lane owns q = lane&15.
// Outputs UNNORMALIZED O (f32) + per-row (m, l), log2 domain.
__global__ __launch_bounds__(256) void attn_mfma(const unsigned short* __restrict__ qb,
                                                 const unsigned short* __restrict__ kb,
                                                 const unsigned short* __restrict__ vT,
                                                 const float* __restrict__ biasg,
                                                 float* __restrict__ Opart,
                                                 float* __restrict__ mpart,
                                                 float* __restrict__ lpart, int N) {
  __shared__ unsigned short P_lds[4][16 * 72];   // per-wave [16 q][64 j], stride 72
  const int w = threadIdx.x >> 6, l = threadIdx.x & 63;
  const int lr = l & 15, lg = l >> 4;
  const int h = blockIdx.y;
  const int s = blockIdx.z;
  const int q0 = blockIdx.x * 64 + w * 16;
  const int hk = h * HD;
  const int jlo = s * (N / NSPLIT), jhi = jlo + N / NSPLIT;
  const float scl2 = 0.17677669529663687f * LOG2E;   // 1/sqrt(32) * log2(e)

  const bf16x8 qf = *reinterpret_cast<const bf16x8*>(qb + (size_t)(q0 + lr) * DD + hk + lg * 8);

  const unsigned short* kbase = kb + hk + lg * 8;
  const unsigned short* vbase = vT + (size_t)hk * N + lg * 8;
  const float* bb = biasg + (size_t)h * N;
  unsigned short* Pw = P_lds[w];
  const int pbase = lr * 72;

  float m_old = -INFINITY, lsum = 0.f;
  const f32x4 zero4 = {0.f, 0.f, 0.f, 0.f};
  f32x4 oacc0 = zero4, oacc1 = zero4;

  // register double-buffered K-frags
  bf16x8 kf0 = *reinterpret_cast<const bf16x8*>(kbase + (size_t)(jlo + lr) * DD);
  bf16x8 kf1 = *reinterpret_cast<const bf16x8*>(kbase + (size_t)(jlo + 16 + lr) * DD);
  bf16x8 kf2 = *reinterpret_cast<const bf16x8*>(kbase + (size_t)(jlo + 32 + lr) * DD);
  bf16x8 kf3 = *reinterpret_cast<const bf16x8*>(kbase + (size_t)(jlo + 48 + lr) * DD);

  for (int j0 = jlo; j0 < jhi; j0 += 64) {
    // V loads for this tile (latency hides under QK + softmax)
    const unsigned short* vrow0 = vbase + (size_t)(lr) * N + j0;        // d-frag 0
    const unsigned short* vrow1 = vbase + (size_t)(16 + lr) * N + j0;   // d-frag 1
    const bf16x8 v00 = *reinterpret_cast<const bf16x8*>(vrow0);         // j-chunk 0
    const bf16x8 v10 = *reinterpret_cast<const bf16x8*>(vrow0 + 32);    // j-chunk 1
    const bf16x8 v01 = *reinterpret_cast<const bf16x8*>(vrow1);
    const bf16x8 v11 = *reinterpret_cast<const bf16x8*>(vrow1 + 32);

    // per-lane bias (log2 domain) for its 16 j values: j = jf*16 + lg*4 + r
    f32x4 bias4[4];
#pragma unroll
    for (int jf = 0; jf < 4; ++jf)
      bias4[jf] = *reinterpret_cast<const f32x4*>(bb + j0 + jf * 16 + lg * 4);

    f32x4 sc[4];
    sc[0] = __builtin_amdgcn_mfma_f32_16x16x32_bf16(kf0, qf, zero4, 0, 0, 0);
    sc[1] = __builtin_amdgcn_mfma_f32_16x16x32_bf16(kf1, qf, zero4, 0, 0, 0);
    sc[2] = __builtin_amdgcn_mfma_f32_16x16x32_bf16(kf2, qf, zero4, 0, 0, 0);
    sc[3] = __builtin_amdgcn_mfma_f32_16x16x32_bf16(kf3, qf, zero4, 0, 0, 0);

    if (j0 + 64 < jhi) {   // prefetch next tile's K-frags
      kf0 = *reinterpret_cast<const bf16x8*>(kbase + (size_t)(j0 + 64 + lr) * DD);
      kf1 = *reinterpret_cast<const bf16x8*>(kbase + (size_t)(j0 + 80 + lr) * DD);
      kf2 = *reinterpret_cast<const bf16x8*>(kbase + (size_t)(j0 + 96 + lr) * DD);
      kf3 = *reinterpret_cast<const bf16x8*>(kbase + (size_t)(j0 + 112 + lr) * DD);
    }

    // scale + bias (log2 domain), local max over this lane's 16 j values
    float p[4][4];
    float mloc = -INFINITY;
#pragma unroll
    for (int jf = 0; jf < 4; ++jf)
#pragma unroll
      for (int r = 0; r < 4; ++r) {
        float t = sc[jf][r] * scl2 + bias4[jf][r];
        p[jf][r] = t;
        mloc = fmaxf(mloc, t);
      }
    mloc = fmaxf(mloc, __shfl_xor(mloc, 16));
    mloc = fmaxf(mloc, __shfl_xor(mloc, 32));

    if (__any(mloc > m_old)) {   // exact defer: rescale only when max grows
      float m_new = fmaxf(m_old, mloc);
      float sf = __builtin_amdgcn_exp2f(m_old - m_new);
      m_old = m_new;
      lsum *= sf;
      float sf0 = __shfl(sf, lg * 4 + 0);
      float sf1 = __shfl(sf, lg * 4 + 1);
      float sf2 = __shfl(sf, lg * 4 + 2);
      float sf3 = __shfl(sf, lg * 4 + 3);
      oacc0[0] *= sf0; oacc0[1] *= sf1; oacc0[2] *= sf2; oacc0[3] *= sf3;
      oacc1[0] *= sf0; oacc1[1] *= sf1; oacc1[2] *= sf2; oacc1[3] *= sf3;
    }

    float rsum = 0.f;
#pragma unroll
    for (int jf = 0; jf < 4; ++jf) {
      float e0 = __builtin_amdgcn_exp2f(p[jf][0] - m_old);
      float e1 = __builtin_amdgcn_exp2f(p[jf][1] - m_old);
      float e2 = __builtin_amdgcn_exp2f(p[jf][2] - m_old);
      float e3 = __builtin_amdgcn_exp2f(p[jf][3] - m_old);
      rsum += (e0 + e1) + (e2 + e3);
      uint2 pk;
      pk.x = pack2(e0, e1);
      pk.y = pack2(e2, e3);
      // P[q=lr][j = jf*16 + lg*4 + r]
      *reinterpret_cast<uint2*>(Pw + pbase + jf * 16 + lg * 4) = pk;
    }
    rsum += __shfl_xor(rsum, 16);
    rsum += __shfl_xor(rsum, 32);
    lsum += rsum;

    // PV: O[16q][32d] += P[16q][64j] * V[64j][32d]
    const bf16x8 pf0 = *reinterpret_cast<const bf16x8*>(Pw + pbase + lg * 8);
    const bf16x8 pf1 = *reinterpret_cast<const bf16x8*>(Pw + pbase + 32 + lg * 8);
    oacc0 = __builtin_amdgcn_mfma_f32_16x16x32_bf16(pf0, v00, oacc0, 0, 0, 0);
    oacc1 = __builtin_amdgcn_mfma_f32_16x16x32_bf16(pf0, v01, oacc1, 0, 0, 0);
    oacc0 = __builtin_amdgcn_mfma_f32_16x16x32_bf16(pf1, v10, oacc0, 0, 0, 0);
    oacc1 = __builtin_amdgcn_mfma_f32_16x16x32_bf16(pf1, v11, oacc1, 0, 0, 0);
  }

  // stats for q = q0 + lr (identical in all lg groups; lg==0 stores)
  const size_t srow = ((size_t)s * NUM_H + h) * N;
  if (lg == 0) {
    mpart[srow + q0 + lr] = m_old;
    lpart[srow + q0 + lr] = lsum;
  }
  // unnormalized O: row q = lg*4 + r, cols d = lr and 16+lr
  float* Ob = Opart + (srow + q0) * 32;
#pragma unroll
  for (int r = 0; r < 4; ++r) {
    Ob[(size_t)(lg * 4 + r) * 32 + lr]      = oacc0[r];
    Ob[(size_t)(lg * 4 + r) * 32 + 16 + lr] = oacc1[r];
  }
}

// ---------------- combine split partials -> bf16 [N][256] -------------------
__global__ __launch_bounds__(256) void combine_kernel(const float* __restrict__ Op,
                                                      const float* __restrict__ mp,
                                                      const float* __restrict__ lp,
                                                      unsigned short* __restrict__ obf, int N) {
  const int idx = blockIdx.x * 256 + threadIdx.x;   // H*N*8 total
  const int d4 = idx & 7;
  const int row = idx >> 3;                         // row = h*N + n
  const size_t HN = (size_t)NUM_H * N;
  float m[NSPLIT], lv[NSPLIT];
#pragma unroll
  for (int s = 0; s < NSPLIT; ++s) {
    m[s]  = mp[s * HN + row];
    lv[s] = lp[s * HN + row];
  }
  float mmax = m[0];
#pragma unroll
  for (int s = 1; s < NSPLIT; ++s) mmax = fmaxf(mmax, m[s]);
  float wsum = 0.f, wgt[NSPLIT];
#pragma unroll
  for (int s = 0; s < NSPLIT; ++s) {
    wgt[s] = __builtin_amdgcn_exp2f(m[s] - mmax);
    wsum += lv[s] * wgt[s];
  }
  const float inv = 1.f / wsum;
  float4 acc = make_float4(0.f, 0.f, 0.f, 0.f);
#pragma unroll
  for (int s = 0; s < NSPLIT; ++s) {
    const float4 v = *reinterpret_cast<const float4*>(Op + (s * HN + row) * 32 + d4 * 4);
    acc.x += wgt[s] * v.x; acc.y += wgt[s] * v.y;
    acc.z += wgt[s] * v.z; acc.w += wgt[s] * v.w;
  }
  const int h = row / N, n = row - h * N;
  uint2 o;
  o.x = pack2(acc.x * inv, acc.y * inv);
  o.y = pack2(acc.z * inv, acc.w * inv);
  *reinterpret_cast<uint2*>(obf + (size_t)n * DD + h * HD + d4 * 4) = o;
}

// ---------------------------------------------------------------------------
extern "C" void kernel_launch(void* const* d_in, const int* in_sizes, int n_in,
                              void* d_out, int out_size, void* d_ws, size_t ws_size,
                              hipStream_t stream) {
  const float* x  = (const float*)d_in[0];
  const int* eidx = (const int*)d_in[1];
  const float* ea = (const float*)d_in[2];
  const float* Wq = (const float*)d_in[3];
  const float* bq = (const float*)d_in[4];
  const float* Wk = (const float*)d_in[5];
  const float* bk = (const float*)d_in[6];
  const float* Wv = (const float*)d_in[7];
  const float* bv = (const float*)d_in[8];
  const float* Wo = (const float*)d_in[9];
  const float* bo = (const float*)d_in[10];
  const float* We = (const float*)d_in[11];
  const float* be = (const float*)d_in[12];
  float* out = (float*)d_out;

  const int N = in_sizes[0] / DD;   // B=1
  const int E = in_sizes[1] / 2;
  const int* tgt = eidx + E;        // edge_index[1]

  // workspace layout
  unsigned short* xb  = (unsigned short*)d_ws;            // [N][256] bf16
  unsigned short* qbf = xb  + (size_t)N * DD;             // [N][256]
  unsigned short* kbf = qbf + (size_t)N * DD;             // [N][256]
  unsigned short* vT  = kbf + (size_t)N * DD;             // [256][N] transposed
  unsigned short* obf = vT  + (size_t)N * DD;             // [N][256]
  unsigned short* WTq = obf + (size_t)N * DD;             // [256][256] bf16 (W^T)
  unsigned short* WTk = WTq + DD * DD;
  unsigned short* WTv = WTk + DD * DD;
  unsigned short* WTo = WTv + DD * DD;
  float* bias  = (float*)(WTo + DD * DD);                 // [H][N] f32 (log2 dom.)
  float* Opart = bias + (size_t)NUM_H * N;                // [S][H][N][32] f32
  float* mpart = Opart + (size_t)NSPLIT * NUM_H * N * 32; // [S][H][N]
  float* lpart = mpart + (size_t)NSPLIT * NUM_H * N;      // [S][H][N]
  int*   sel   = (int*)(lpart + (size_t)NSPLIT * NUM_H * N); // [N]

  sel_init_kernel<<<(N + 255) / 256, 256, 0, stream>>>(sel, N);
  sel_scatter_kernel<<<(E + 255) / 256, 256, 0, stream>>>(tgt, sel, E);
  bias_build_kernel<<<(N + 255) / 256, 256, 0, stream>>>(sel, ea, We, be, bias, N);

  cvt_x_kernel<<<(N * DD) / 1024, 256, 0, stream>>>(x, xb);
  dim3 wg(8, 8, 4);
  cvt_wt_all<<<wg, 256, 0, stream>>>(Wq, Wk, Wv, Wo, WTq, WTk, WTv, WTo);

  dim3 pg(N / 64, DD / 32, 3);
  proj_qkv<<<pg, 256, 0, stream>>>(xb, WTq, WTk, WTv, bq, bk, bv, qbf, kbf, vT, N);

  dim3 ag(N / 64, NUM_H, NSPLIT);
  attn_mfma<<<ag, 256, 0, stream>>>(qbf, kbf, vT, bias, Opart, mpart, lpart, N);

  combine_kernel<<<(NUM_H * N * 8) / 256, 256, 0, stream>>>(Opart, mpart, lpart, obf, N);

  dim3 og(N / 64, DD / 32);
  proj_out<<<og, 256, 0, stream>>>(obf, WTo, bo, out, N);
}

// Round 5
// 184.921 us; speedup vs baseline: 2.8351x; 1.0012x over previous
//
#include <hip/hip_runtime.h>
#include <hip/hip_bf16.h>
#include <math.h>

#define NUM_H 8
#define HD 32
#define DD 256
#define NSPLIT 4

typedef __attribute__((ext_vector_type(8))) short bf16x8;
typedef __attribute__((ext_vector_type(4))) float f32x4;
typedef __attribute__((ext_vector_type(4))) unsigned short u16x4;

__device__ __forceinline__ unsigned short f2b(float f) {
  unsigned u = __builtin_bit_cast(unsigned, f);
  u += 0x7FFFu + ((u >> 16) & 1u);   // RNE
  return (unsigned short)(u >> 16);
}

__device__ __forceinline__ unsigned pack2(float a, float b) {
  float2 t; t.x = a; t.y = b;
  __hip_bfloat162 r = __float22bfloat162_rn(t);   // v_cvt_pk_bf16_f32
  unsigned u;
  __builtin_memcpy(&u, &r, sizeof(u));            // bit_cast rejected: not trivially copyable
  return u;
}

#define LOG2E 1.4426950408889634f

// ---------------- edge bias: last-write-wins scatter (numpy semantics) -----
__global__ void sel_init_kernel(int* __restrict__ sel, int N) {
  int t = blockIdx.x * 256 + threadIdx.x;
  if (t < N) sel[t] = -1;
}

__global__ void sel_scatter_kernel(const int* __restrict__ tgt, int* __restrict__ sel, int E) {
  int e = blockIdx.x * 256 + threadIdx.x;
  if (e < E) atomicMax(&sel[tgt[e]], e);   // max e == last occurrence wins
}

// stores bias * log2(e)  (softmax done in exp2 domain)
__global__ void bias_build_kernel(const int* __restrict__ sel, const float* __restrict__ ea,
                                  const float* __restrict__ We, const float* __restrict__ be,
                                  float* __restrict__ bias, int N) {
  int t = blockIdx.x * 256 + threadIdx.x;
  if (t >= N) return;
  int e = sel[t];
  bool has = (e >= 0);
  float a0 = 0.f, a1 = 0.f, a2 = 0.f;
  if (has) {
    a0 = ea[3 * (size_t)e];
    a1 = ea[3 * (size_t)e + 1];
    a2 = ea[3 * (size_t)e + 2];
  }
#pragma unroll
  for (int h = 0; h < NUM_H; ++h) {
    float v = has ? (a0 * We[h] + a1 * We[NUM_H + h] + a2 * We[2 * NUM_H + h] + be[h]) : 0.f;
    bias[(size_t)h * N + t] = v * LOG2E;   // [H][N]
  }
}

// ---------------- fp32 -> bf16 converts ------------------------------------
__global__ void cvt_x_kernel(const float* __restrict__ x, unsigned short* __restrict__ xb) {
  int i = blockIdx.x * 256 + threadIdx.x;   // 4 elems per thread
  const float4 v = *reinterpret_cast<const float4*>(x + (size_t)i * 4);
  uint2 o;
  o.x = pack2(v.x, v.y);
  o.y = pack2(v.z, v.w);
  *reinterpret_cast<uint2*>(xb + (size_t)i * 4) = o;
}

// WT[c][k] = bf16(W[k][c]) for 4 weights, LDS tile transpose. z picks the matrix.
__global__ void cvt_wt_all(const float* __restrict__ W0, const float* __restrict__ W1,
                           const float* __restrict__ W2, const float* __restrict__ W3,
                           unsigned short* __restrict__ T0, unsigned short* __restrict__ T1,
                           unsigned short* __restrict__ T2, unsigned short* __restrict__ T3) {
  __shared__ float t[32][33];
  const int z = blockIdx.z;
  const float* W = (z == 0) ? W0 : (z == 1) ? W1 : (z == 2) ? W2 : W3;
  unsigned short* WT = (z == 0) ? T0 : (z == 1) ? T1 : (z == 2) ? T2 : T3;
  const int bx = blockIdx.x, by = blockIdx.y;
  const int lx = threadIdx.x & 31, ly = threadIdx.x >> 5;   // 256 thr: ly 0..7
#pragma unroll
  for (int r = 0; r < 32; r += 8)
    t[r + ly][lx] = W[(size_t)(bx * 32 + r + ly) * DD + by * 32 + lx];
  __syncthreads();
#pragma unroll
  for (int r = 0; r < 32; r += 8)
    WT[(size_t)(by * 32 + r + ly) * DD + bx * 32 + lx] = f2b(t[lx][r + ly]);
}

// ---------------- MFMA projection core -------------------------------------
// wave tile 16n x 32c, K-loop 8 x mfma_16x16x32. Operands from global (L2).
__device__ __forceinline__ void proj_core(const unsigned short* __restrict__ Xb,
                                          const unsigned short* __restrict__ WT,
                                          int n0, int c0, int lr, int lg,
                                          f32x4& acc0, f32x4& acc1) {
  const f32x4 zero4 = {0.f, 0.f, 0.f, 0.f};
  acc0 = zero4; acc1 = zero4;
  const unsigned short* ap  = Xb + (size_t)(n0 + lr) * DD + lg * 8;
  const unsigned short* bp0 = WT + (size_t)(c0 + lr) * DD + lg * 8;
  const unsigned short* bp1 = bp0 + 16 * DD;
#pragma unroll
  for (int kk = 0; kk < 8; ++kk) {
    bf16x8 a  = *reinterpret_cast<const bf16x8*>(ap + kk * 32);
    bf16x8 b0 = *reinterpret_cast<const bf16x8*>(bp0 + kk * 32);
    bf16x8 b1 = *reinterpret_cast<const bf16x8*>(bp1 + kk * 32);
    acc0 = __builtin_amdgcn_mfma_f32_16x16x32_bf16(a, b0, acc0, 0, 0, 0);
    acc1 = __builtin_amdgcn_mfma_f32_16x16x32_bf16(a, b1, acc1, 0, 0, 0);
  }
}

// fused Q/K/V projection; z = 0:Q (bf16 [N][256]), 1:K (bf16 [N][256]),
// 2:V (bf16 transposed [256][N])
__global__ __launch_bounds__(256) void proj_qkv(const unsigned short* __restrict__ Xb,
                                                const unsigned short* __restrict__ WTq,
                                                const unsigned short* __restrict__ WTk,
                                                const unsigned short* __restrict__ WTv,
                                                const float* __restrict__ bq,
                                                const float* __restrict__ bk,
                                                const float* __restrict__ bv,
                                                unsigned short* __restrict__ qbf,
                                                unsigned short* __restrict__ kbf,
                                                unsigned short* __restrict__ vT, int N) {
  const int z = blockIdx.z;
  const unsigned short* WT = (z == 0) ? WTq : (z == 1) ? WTk : WTv;
  const float* bias = (z == 0) ? bq : (z == 1) ? bk : bv;
  const int w = threadIdx.x >> 6, l = threadIdx.x & 63;
  const int lr = l & 15, lg = l >> 4;
  const int n0 = (blockIdx.x * 4 + w) * 16;
  const int c0 = blockIdx.y * 32;
  f32x4 acc0, acc1;
  proj_core(Xb, WT, n0, c0, lr, lg, acc0, acc1);
  const float bc0 = bias[c0 + lr], bc1 = bias[c0 + 16 + lr];
  if (z < 2) {
    unsigned short* Yb = z ? kbf : qbf;
#pragma unroll
    for (int r = 0; r < 4; ++r) {
      Yb[(size_t)(n0 + lg * 4 + r) * DD + c0 + lr]      = f2b(acc0[r] + bc0);
      Yb[(size_t)(n0 + lg * 4 + r) * DD + c0 + 16 + lr] = f2b(acc1[r] + bc1);
    }
  } else {
    uint2 o0, o1;
    o0.x = pack2(acc0[0] + bc0, acc0[1] + bc0);
    o0.y = pack2(acc0[2] + bc0, acc0[3] + bc0);
    o1.x = pack2(acc1[0] + bc1, acc1[1] + bc1);
    o1.y = pack2(acc1[2] + bc1, acc1[3] + bc1);
    *reinterpret_cast<uint2*>(vT + (size_t)(c0 + lr) * N + n0 + lg * 4)      = o0;
    *reinterpret_cast<uint2*>(vT + (size_t)(c0 + 16 + lr) * N + n0 + lg * 4) = o1;
  }
}

// output projection: f32 out
__global__ __launch_bounds__(256) void proj_out(const unsigned short* __restrict__ Xb,
                                                const unsigned short* __restrict__ WT,
                                                const float* __restrict__ bias,
                                                float* __restrict__ Y, int N) {
  const int w = threadIdx.x >> 6, l = threadIdx.x & 63;
  const int lr = l & 15, lg = l >> 4;
  const int n0 = (blockIdx.x * 4 + w) * 16;
  const int c0 = blockIdx.y * 32;
  f32x4 acc0, acc1;
  proj_core(Xb, WT, n0, c0, lr, lg, acc0, acc1);
  const float bc0 = bias[c0 + lr], bc1 = bias[c0 + 16 + lr];
#pragma unroll
  for (int r = 0; r < 4; ++r) {
    Y[(size_t)(n0 + lg * 4 + r) * DD + c0 + lr]      = acc0[r] + bc0;
    Y[(size_t)(n0 + lg * 4 + r) * DD + c0 + 16 + lr] = acc1[r] + bc1;
  }
}

// ---------------- flash attention, bf16 MFMA, split-j, XCD-clustered --------
// 1-D grid of (N/64)*H*NSPLIT. Decode: h = bid&7 -> with round-robin
// workgroup->XCD dispatch, all blocks of head h land on XCD h, so each XCD's
// L2 working set is ONE head's K/V/Q (~0.8 MB << 4 MiB) instead of all 8
// heads (L2 thrash -> L3/HBM latency was the R4 stall; FETCH 17.9MB vs 6MB).
// Block: 4 independent waves (no barriers). Wave: 16 q-rows.
// Swapped QK^T: S^T = mfma(K_frag, Q_frag) -> lane owns q = lane&15.
// Outputs UNNORMALIZED O (f32) + per-row (m, l), log2 domain.
__global__ __launch_bounds__(256) void attn_mfma(const unsigned short* __restrict__ qb,
                                                 const unsigned short* __restrict__ kb,
                                                 const unsigned short* __restrict__ vT,
                                                 const float* __restrict__ biasg,
                                                 float* __restrict__ Opart,
                                                 float* __restrict__ mpart,
                                                 float* __restrict__ lpart, int N) {
  __shared__ unsigned short P_lds[4][16 * 72];   // per-wave [16 q][64 j], stride 72
  const int w = threadIdx.x >> 6, l = threadIdx.x & 63;
  const int lr = l & 15, lg = l >> 4;
  const int bid = blockIdx.x;
  const int h = bid & 7;                 // XCD-clustered head
  const int rem = bid >> 3;
  const int qblk = rem & 63;
  const int s = rem >> 6;
  const int q0 = qblk * 64 + w * 16;
  const int hk = h * HD;
  const int jlo = s * (N / NSPLIT), jhi = jlo + N / NSPLIT;
  const float scl2 = 0.17677669529663687f * LOG2E;   // 1/sqrt(32) * log2(e)

  const bf16x8 qf = *reinterpret_cast<const bf16x8*>(qb + (size_t)(q0 + lr) * DD + hk + lg * 8);

  const unsigned short* kbase = kb + hk + lg * 8;
  const unsigned short* vbase = vT + (size_t)hk * N + lg * 8;
  const float* bb = biasg + (size_t)h * N;
  unsigned short* Pw = P_lds[w];
  const int pbase = lr * 72;

  float m_old = -INFINITY, lsum = 0.f;
  const f32x4 zero4 = {0.f, 0.f, 0.f, 0.f};
  f32x4 oacc0 = zero4, oacc1 = zero4;

  // register double-buffered K-frags
  bf16x8 kf0 = *reinterpret_cast<const bf16x8*>(kbase + (size_t)(jlo + lr) * DD);
  bf16x8 kf1 = *reinterpret_cast<const bf16x8*>(kbase + (size_t)(jlo + 16 + lr) * DD);
  bf16x8 kf2 = *reinterpret_cast<const bf16x8*>(kbase + (size_t)(jlo + 32 + lr) * DD);
  bf16x8 kf3 = *reinterpret_cast<const bf16x8*>(kbase + (size_t)(jlo + 48 + lr) * DD);

  for (int j0 = jlo; j0 < jhi; j0 += 64) {
    // V loads for this tile (latency hides under QK + softmax)
    const unsigned short* vrow0 = vbase + (size_t)(lr) * N + j0;        // d-frag 0
    const unsigned short* vrow1 = vbase + (size_t)(16 + lr) * N + j0;   // d-frag 1
    const bf16x8 v00 = *reinterpret_cast<const bf16x8*>(vrow0);         // j-chunk 0
    const bf16x8 v10 = *reinterpret_cast<const bf16x8*>(vrow0 + 32);    // j-chunk 1
    const bf16x8 v01 = *reinterpret_cast<const bf16x8*>(vrow1);
    const bf16x8 v11 = *reinterpret_cast<const bf16x8*>(vrow1 + 32);

    // per-lane bias (log2 domain) for its 16 j values: j = jf*16 + lg*4 + r
    f32x4 bias4[4];
#pragma unroll
    for (int jf = 0; jf < 4; ++jf)
      bias4[jf] = *reinterpret_cast<const f32x4*>(bb + j0 + jf * 16 + lg * 4);

    f32x4 sc[4];
    __builtin_amdgcn_s_setprio(1);
    sc[0] = __builtin_amdgcn_mfma_f32_16x16x32_bf16(kf0, qf, zero4, 0, 0, 0);
    sc[1] = __builtin_amdgcn_mfma_f32_16x16x32_bf16(kf1, qf, zero4, 0, 0, 0);
    sc[2] = __builtin_amdgcn_mfma_f32_16x16x32_bf16(kf2, qf, zero4, 0, 0, 0);
    sc[3] = __builtin_amdgcn_mfma_f32_16x16x32_bf16(kf3, qf, zero4, 0, 0, 0);
    __builtin_amdgcn_s_setprio(0);

    if (j0 + 64 < jhi) {   // prefetch next tile's K-frags
      kf0 = *reinterpret_cast<const bf16x8*>(kbase + (size_t)(j0 + 64 + lr) * DD);
      kf1 = *reinterpret_cast<const bf16x8*>(kbase + (size_t)(j0 + 80 + lr) * DD);
      kf2 = *reinterpret_cast<const bf16x8*>(kbase + (size_t)(j0 + 96 + lr) * DD);
      kf3 = *reinterpret_cast<const bf16x8*>(kbase + (size_t)(j0 + 112 + lr) * DD);
    }

    // scale + bias (log2 domain), local max over this lane's 16 j values
    float p[4][4];
    float mloc = -INFINITY;
#pragma unroll
    for (int jf = 0; jf < 4; ++jf)
#pragma unroll
      for (int r = 0; r < 4; ++r) {
        float t = sc[jf][r] * scl2 + bias4[jf][r];
        p[jf][r] = t;
        mloc = fmaxf(mloc, t);
      }
    mloc = fmaxf(mloc, __shfl_xor(mloc, 16));
    mloc = fmaxf(mloc, __shfl_xor(mloc, 32));

    if (__any(mloc > m_old)) {   // exact defer: rescale only when max grows
      float m_new = fmaxf(m_old, mloc);
      float sf = __builtin_amdgcn_exp2f(m_old - m_new);
      m_old = m_new;
      lsum *= sf;
      float sf0 = __shfl(sf, lg * 4 + 0);
      float sf1 = __shfl(sf, lg * 4 + 1);
      float sf2 = __shfl(sf, lg * 4 + 2);
      float sf3 = __shfl(sf, lg * 4 + 3);
      oacc0[0] *= sf0; oacc0[1] *= sf1; oacc0[2] *= sf2; oacc0[3] *= sf3;
      oacc1[0] *= sf0; oacc1[1] *= sf1; oacc1[2] *= sf2; oacc1[3] *= sf3;
    }

    float rsum = 0.f;
#pragma unroll
    for (int jf = 0; jf < 4; ++jf) {
      float e0 = __builtin_amdgcn_exp2f(p[jf][0] - m_old);
      float e1 = __builtin_amdgcn_exp2f(p[jf][1] - m_old);
      float e2 = __builtin_amdgcn_exp2f(p[jf][2] - m_old);
      float e3 = __builtin_amdgcn_exp2f(p[jf][3] - m_old);
      rsum += (e0 + e1) + (e2 + e3);
      uint2 pk;
      pk.x = pack2(e0, e1);
      pk.y = pack2(e2, e3);
      // P[q=lr][j = jf*16 + lg*4 + r]
      *reinterpret_cast<uint2*>(Pw + pbase + jf * 16 + lg * 4) = pk;
    }
    rsum += __shfl_xor(rsum, 16);
    rsum += __shfl_xor(rsum, 32);
    lsum += rsum;

    // PV: O[16q][32d] += P[16q][64j] * V[64j][32d]
    const bf16x8 pf0 = *reinterpret_cast<const bf16x8*>(Pw + pbase + lg * 8);
    const bf16x8 pf1 = *reinterpret_cast<const bf16x8*>(Pw + pbase + 32 + lg * 8);
    __builtin_amdgcn_s_setprio(1);
    oacc0 = __builtin_amdgcn_mfma_f32_16x16x32_bf16(pf0, v00, oacc0, 0, 0, 0);
    oacc1 = __builtin_amdgcn_mfma_f32_16x16x32_bf16(pf0, v01, oacc1, 0, 0, 0);
    oacc0 = __builtin_amdgcn_mfma_f32_16x16x32_bf16(pf1, v10, oacc0, 0, 0, 0);
    oacc1 = __builtin_amdgcn_mfma_f32_16x16x32_bf16(pf1, v11, oacc1, 0, 0, 0);
    __builtin_amdgcn_s_setprio(0);
  }

  // stats for q = q0 + lr (identical in all lg groups; lg==0 stores)
  const size_t srow = ((size_t)s * NUM_H + h) * N;
  if (lg == 0) {
    mpart[srow + q0 + lr] = m_old;
    lpart[srow + q0 + lr] = lsum;
  }
  // unnormalized O: row q = lg*4 + r, cols d = lr and 16+lr
  float* Ob = Opart + (srow + q0) * 32;
#pragma unroll
  for (int r = 0; r < 4; ++r) {
    Ob[(size_t)(lg * 4 + r) * 32 + lr]      = oacc0[r];
    Ob[(size_t)(lg * 4 + r) * 32 + 16 + lr] = oacc1[r];
  }
}

// ---------------- combine split partials -> bf16 [N][256] -------------------
__global__ __launch_bounds__(256) void combine_kernel(const float* __restrict__ Op,
                                                      const float* __restrict__ mp,
                                                      const float* __restrict__ lp,
                                                      unsigned short* __restrict__ obf, int N) {
  const int idx = blockIdx.x * 256 + threadIdx.x;   // H*N*8 total
  const int d4 = idx & 7;
  const int row = idx >> 3;                         // row = h*N + n
  const size_t HN = (size_t)NUM_H * N;
  float m[NSPLIT], lv[NSPLIT];
#pragma unroll
  for (int s = 0; s < NSPLIT; ++s) {
    m[s]  = mp[s * HN + row];
    lv[s] = lp[s * HN + row];
  }
  float mmax = m[0];
#pragma unroll
  for (int s = 1; s < NSPLIT; ++s) mmax = fmaxf(mmax, m[s]);
  float wsum = 0.f, wgt[NSPLIT];
#pragma unroll
  for (int s = 0; s < NSPLIT; ++s) {
    wgt[s] = __builtin_amdgcn_exp2f(m[s] - mmax);
    wsum += lv[s] * wgt[s];
  }
  const float inv = 1.f / wsum;
  float4 acc = make_float4(0.f, 0.f, 0.f, 0.f);
#pragma unroll
  for (int s = 0; s < NSPLIT; ++s) {
    const float4 v = *reinterpret_cast<const float4*>(Op + (s * HN + row) * 32 + d4 * 4);
    acc.x += wgt[s] * v.x; acc.y += wgt[s] * v.y;
    acc.z += wgt[s] * v.z; acc.w += wgt[s] * v.w;
  }
  const int h = row / N, n = row - h * N;
  uint2 o;
  o.x = pack2(acc.x * inv, acc.y * inv);
  o.y = pack2(acc.z * inv, acc.w * inv);
  *reinterpret_cast<uint2*>(obf + (size_t)n * DD + h * HD + d4 * 4) = o;
}

// ---------------------------------------------------------------------------
extern "C" void kernel_launch(void* const* d_in, const int* in_sizes, int n_in,
                              void* d_out, int out_size, void* d_ws, size_t ws_size,
                              hipStream_t stream) {
  const float* x  = (const float*)d_in[0];
  const int* eidx = (const int*)d_in[1];
  const float* ea = (const float*)d_in[2];
  const float* Wq = (const float*)d_in[3];
  const float* bq = (const float*)d_in[4];
  const float* Wk = (const float*)d_in[5];
  const float* bk = (const float*)d_in[6];
  const float* Wv = (const float*)d_in[7];
  const float* bv = (const float*)d_in[8];
  const float* Wo = (const float*)d_in[9];
  const float* bo = (const float*)d_in[10];
  const float* We = (const float*)d_in[11];
  const float* be = (const float*)d_in[12];
  float* out = (float*)d_out;

  const int N = in_sizes[0] / DD;   // B=1
  const int E = in_sizes[1] / 2;
  const int* tgt = eidx + E;        // edge_index[1]

  // workspace layout
  unsigned short* xb  = (unsigned short*)d_ws;            // [N][256] bf16
  unsigned short* qbf = xb  + (size_t)N * DD;             // [N][256]
  unsigned short* kbf = qbf + (size_t)N * DD;             // [N][256]
  unsigned short* vT  = kbf + (size_t)N * DD;             // [256][N] transposed
  unsigned short* obf = vT  + (size_t)N * DD;             // [N][256]
  unsigned short* WTq = obf + (size_t)N * DD;             // [256][256] bf16 (W^T)
  unsigned short* WTk = WTq + DD * DD;
  unsigned short* WTv = WTk + DD * DD;
  unsigned short* WTo = WTv + DD * DD;
  float* bias  = (float*)(WTo + DD * DD);                 // [H][N] f32 (log2 dom.)
  float* Opart = bias + (size_t)NUM_H * N;                // [S][H][N][32] f32
  float* mpart = Opart + (size_t)NSPLIT * NUM_H * N * 32; // [S][H][N]
  float* lpart = mpart + (size_t)NSPLIT * NUM_H * N;      // [S][H][N]
  int*   sel   = (int*)(lpart + (size_t)NSPLIT * NUM_H * N); // [N]

  sel_init_kernel<<<(N + 255) / 256, 256, 0, stream>>>(sel, N);
  sel_scatter_kernel<<<(E + 255) / 256, 256, 0, stream>>>(tgt, sel, E);
  bias_build_kernel<<<(N + 255) / 256, 256, 0, stream>>>(sel, ea, We, be, bias, N);

  cvt_x_kernel<<<(N * DD) / 1024, 256, 0, stream>>>(x, xb);
  dim3 wg(8, 8, 4);
  cvt_wt_all<<<wg, 256, 0, stream>>>(Wq, Wk, Wv, Wo, WTq, WTk, WTv, WTo);

  dim3 pg(N / 64, DD / 32, 3);
  proj_qkv<<<pg, 256, 0, stream>>>(xb, WTq, WTk, WTv, bq, bk, bv, qbf, kbf, vT, N);

  // 1-D grid, head = bid&7 (XCD-clustered)
  attn_mfma<<<(N / 64) * NUM_H * NSPLIT, 256, 0, stream>>>(qbf, kbf, vT, bias,
                                                           Opart, mpart, lpart, N);

  combine_kernel<<<(NUM_H * N * 8) / 256, 256, 0, stream>>>(Opart, mpart, lpart, obf, N);

  dim3 og(N / 64, DD / 32);
  proj_out<<<og, 256, 0, stream>>>(obf, WTo, bo, out, N);
}

// Round 6
// 115.266 us; speedup vs baseline: 4.5483x; 1.6043x over previous
//
#include <hip/hip_runtime.h>
#include <hip/hip_bf16.h>
#include <math.h>

#define NUM_H 8
#define HD 32
#define DD 256
#define NSPLIT 4

typedef __attribute__((ext_vector_type(8))) short bf16x8;
typedef __attribute__((ext_vector_type(4))) float f32x4;
typedef __attribute__((ext_vector_type(4))) unsigned short u16x4;

__device__ __forceinline__ unsigned short f2b(float f) {
  unsigned u = __builtin_bit_cast(unsigned, f);
  u += 0x7FFFu + ((u >> 16) & 1u);   // RNE
  return (unsigned short)(u >> 16);
}

__device__ __forceinline__ unsigned pack2(float a, float b) {
  float2 t; t.x = a; t.y = b;
  __hip_bfloat162 r = __float22bfloat162_rn(t);   // v_cvt_pk_bf16_f32
  unsigned u;
  __builtin_memcpy(&u, &r, sizeof(u));            // bit_cast rejected: not trivially copyable
  return u;
}

#define LOG2E 1.4426950408889634f

// ---------------- edge bias: last-write-wins scatter (numpy semantics) -----
__global__ void sel_init_kernel(int* __restrict__ sel, int N) {
  int t = blockIdx.x * 256 + threadIdx.x;
  if (t < N) sel[t] = -1;
}

__global__ void sel_scatter_kernel(const int* __restrict__ tgt, int* __restrict__ sel, int E) {
  int e = blockIdx.x * 256 + threadIdx.x;
  if (e < E) atomicMax(&sel[tgt[e]], e);   // max e == last occurrence wins
}

// stores bias * log2(e)  (softmax done in exp2 domain)
__global__ void bias_build_kernel(const int* __restrict__ sel, const float* __restrict__ ea,
                                  const float* __restrict__ We, const float* __restrict__ be,
                                  float* __restrict__ bias, int N) {
  int t = blockIdx.x * 256 + threadIdx.x;
  if (t >= N) return;
  int e = sel[t];
  bool has = (e >= 0);
  float a0 = 0.f, a1 = 0.f, a2 = 0.f;
  if (has) {
    a0 = ea[3 * (size_t)e];
    a1 = ea[3 * (size_t)e + 1];
    a2 = ea[3 * (size_t)e + 2];
  }
#pragma unroll
  for (int h = 0; h < NUM_H; ++h) {
    float v = has ? (a0 * We[h] + a1 * We[NUM_H + h] + a2 * We[2 * NUM_H + h] + be[h]) : 0.f;
    bias[(size_t)h * N + t] = v * LOG2E;   // [H][N]
  }
}

// ---------------- fp32 -> bf16 converts ------------------------------------
__global__ void cvt_x_kernel(const float* __restrict__ x, unsigned short* __restrict__ xb) {
  int i = blockIdx.x * 256 + threadIdx.x;   // 4 elems per thread
  const float4 v = *reinterpret_cast<const float4*>(x + (size_t)i * 4);
  uint2 o;
  o.x = pack2(v.x, v.y);
  o.y = pack2(v.z, v.w);
  *reinterpret_cast<uint2*>(xb + (size_t)i * 4) = o;
}

// WT[c][k] = bf16(W[k][c]) for 4 weights, LDS tile transpose. z picks the matrix.
__global__ void cvt_wt_all(const float* __restrict__ W0, const float* __restrict__ W1,
                           const float* __restrict__ W2, const float* __restrict__ W3,
                           unsigned short* __restrict__ T0, unsigned short* __restrict__ T1,
                           unsigned short* __restrict__ T2, unsigned short* __restrict__ T3) {
  __shared__ float t[32][33];
  const int z = blockIdx.z;
  const float* W = (z == 0) ? W0 : (z == 1) ? W1 : (z == 2) ? W2 : W3;
  unsigned short* WT = (z == 0) ? T0 : (z == 1) ? T1 : (z == 2) ? T2 : T3;
  const int bx = blockIdx.x, by = blockIdx.y;
  const int lx = threadIdx.x & 31, ly = threadIdx.x >> 5;   // 256 thr: ly 0..7
#pragma unroll
  for (int r = 0; r < 32; r += 8)
    t[r + ly][lx] = W[(size_t)(bx * 32 + r + ly) * DD + by * 32 + lx];
  __syncthreads();
#pragma unroll
  for (int r = 0; r < 32; r += 8)
    WT[(size_t)(by * 32 + r + ly) * DD + bx * 32 + lx] = f2b(t[lx][r + ly]);
}

// ---------------- MFMA projection core -------------------------------------
// wave tile 16n x 32c, K-loop 8 x mfma_16x16x32. Operands from global (L2).
__device__ __forceinline__ void proj_core(const unsigned short* __restrict__ Xb,
                                          const unsigned short* __restrict__ WT,
                                          int n0, int c0, int lr, int lg,
                                          f32x4& acc0, f32x4& acc1) {
  const f32x4 zero4 = {0.f, 0.f, 0.f, 0.f};
  acc0 = zero4; acc1 = zero4;
  const unsigned short* ap  = Xb + (size_t)(n0 + lr) * DD + lg * 8;
  const unsigned short* bp0 = WT + (size_t)(c0 + lr) * DD + lg * 8;
  const unsigned short* bp1 = bp0 + 16 * DD;
#pragma unroll
  for (int kk = 0; kk < 8; ++kk) {
    bf16x8 a  = *reinterpret_cast<const bf16x8*>(ap + kk * 32);
    bf16x8 b0 = *reinterpret_cast<const bf16x8*>(bp0 + kk * 32);
    bf16x8 b1 = *reinterpret_cast<const bf16x8*>(bp1 + kk * 32);
    acc0 = __builtin_amdgcn_mfma_f32_16x16x32_bf16(a, b0, acc0, 0, 0, 0);
    acc1 = __builtin_amdgcn_mfma_f32_16x16x32_bf16(a, b1, acc1, 0, 0, 0);
  }
}

// fused Q/K/V projection; z = 0:Q (bf16 [N][256]), 1:K (bf16 [N][256]),
// 2:V (bf16 transposed [256][N])
__global__ __launch_bounds__(256) void proj_qkv(const unsigned short* __restrict__ Xb,
                                                const unsigned short* __restrict__ WTq,
                                                const unsigned short* __restrict__ WTk,
                                                const unsigned short* __restrict__ WTv,
                                                const float* __restrict__ bq,
                                                const float* __restrict__ bk,
                                                const float* __restrict__ bv,
                                                unsigned short* __restrict__ qbf,
                                                unsigned short* __restrict__ kbf,
                                                unsigned short* __restrict__ vT, int N) {
  const int z = blockIdx.z;
  const unsigned short* WT = (z == 0) ? WTq : (z == 1) ? WTk : WTv;
  const float* bias = (z == 0) ? bq : (z == 1) ? bk : bv;
  const int w = threadIdx.x >> 6, l = threadIdx.x & 63;
  const int lr = l & 15, lg = l >> 4;
  const int n0 = (blockIdx.x * 4 + w) * 16;
  const int c0 = blockIdx.y * 32;
  f32x4 acc0, acc1;
  proj_core(Xb, WT, n0, c0, lr, lg, acc0, acc1);
  const float bc0 = bias[c0 + lr], bc1 = bias[c0 + 16 + lr];
  if (z < 2) {
    unsigned short* Yb = z ? kbf : qbf;
#pragma unroll
    for (int r = 0; r < 4; ++r) {
      Yb[(size_t)(n0 + lg * 4 + r) * DD + c0 + lr]      = f2b(acc0[r] + bc0);
      Yb[(size_t)(n0 + lg * 4 + r) * DD + c0 + 16 + lr] = f2b(acc1[r] + bc1);
    }
  } else {
    uint2 o0, o1;
    o0.x = pack2(acc0[0] + bc0, acc0[1] + bc0);
    o0.y = pack2(acc0[2] + bc0, acc0[3] + bc0);
    o1.x = pack2(acc1[0] + bc1, acc1[1] + bc1);
    o1.y = pack2(acc1[2] + bc1, acc1[3] + bc1);
    *reinterpret_cast<uint2*>(vT + (size_t)(c0 + lr) * N + n0 + lg * 4)      = o0;
    *reinterpret_cast<uint2*>(vT + (size_t)(c0 + 16 + lr) * N + n0 + lg * 4) = o1;
  }
}

// output projection: f32 out
__global__ __launch_bounds__(256) void proj_out(const unsigned short* __restrict__ Xb,
                                                const unsigned short* __restrict__ WT,
                                                const float* __restrict__ bias,
                                                float* __restrict__ Y, int N) {
  const int w = threadIdx.x >> 6, l = threadIdx.x & 63;
  const int lr = l & 15, lg = l >> 4;
  const int n0 = (blockIdx.x * 4 + w) * 16;
  const int c0 = blockIdx.y * 32;
  f32x4 acc0, acc1;
  proj_core(Xb, WT, n0, c0, lr, lg, acc0, acc1);
  const float bc0 = bias[c0 + lr], bc1 = bias[c0 + 16 + lr];
#pragma unroll
  for (int r = 0; r < 4; ++r) {
    Y[(size_t)(n0 + lg * 4 + r) * DD + c0 + lr]      = acc0[r] + bc0;
    Y[(size_t)(n0 + lg * 4 + r) * DD + c0 + 16 + lr] = acc1[r] + bc1;
  }
}

// ---------------- flash attention, bf16 MFMA, split-j, LDS-staged K/V -------
// 1-D grid of (N/64)*H*NSPLIT, h = bid&7 (XCD-clustered: one head per XCD L2).
// NEW (R6): K and V tiles staged cooperatively into LDS once per block-tile
// (coalesced 16B/lane loads), shared by all 4 waves. Replaces 4x-redundant
// per-wave 512B/8KB-stride global gathers (16 transactions per wave64 load)
// that serialized the per-iteration critical path. Frag-read layouts are
// kg-major / js-major: 16 consecutive lanes -> 16 consecutive 16B LDS slots.
// T14: next tile's global loads issued right after barrier, written next iter.
__global__ __launch_bounds__(256, 6) void attn_mfma(const unsigned short* __restrict__ qb,
                                                    const unsigned short* __restrict__ kb,
                                                    const unsigned short* __restrict__ vT,
                                                    const float* __restrict__ biasg,
                                                    float* __restrict__ Opart,
                                                    float* __restrict__ mpart,
                                                    float* __restrict__ lpart, int N) {
  __shared__ unsigned short Ks[4 * 64 * 8];      // [kg:4][j:64][8]  4KB
  __shared__ unsigned short Vs[8 * 32 * 8];      // [js:8][d:32][8]  4KB
  __shared__ unsigned short P_lds[4][16 * 72];   // per-wave [16 q][64 j]
  const int tid = threadIdx.x;
  const int w = tid >> 6, l = tid & 63;
  const int lr = l & 15, lg = l >> 4;
  const int bid = blockIdx.x;
  const int h = bid & 7;                 // XCD-clustered head
  const int rem = bid >> 3;
  const int qblk = rem & 63;
  const int s = rem >> 6;
  const int q0 = qblk * 64 + w * 16;
  const int hk = h * HD;
  const int jlo = s * (N / NSPLIT), jhi = jlo + N / NSPLIT;
  const float scl2 = 0.17677669529663687f * LOG2E;   // 1/sqrt(32) * log2(e)

  const bf16x8 qf = *reinterpret_cast<const bf16x8*>(qb + (size_t)(q0 + lr) * DD + hk + lg * 8);

  // staging pointers: K: j = tid>>2, kg = tid&3 (4 threads per 64B line, coalesced)
  //                   V: d = tid>>3, js = tid&7 (8 threads per 128B row, coalesced)
  const unsigned short* kgp = kb + hk + (tid & 3) * 8;
  const unsigned short* vgp = vT + (size_t)(hk + (tid >> 3)) * N + (tid & 7) * 8;
  unsigned short* kls = Ks + (tid & 3) * 512 + (tid >> 2) * 8;
  unsigned short* vls = Vs + (tid & 7) * 256 + (tid >> 3) * 8;
  // frag-read pointers
  const unsigned short* kfb = Ks + lg * 512 + lr * 8;   // A-frag: K[jf*16+lr][lg*8..]
  const unsigned short* vfb = Vs + lg * 256 + lr * 8;   // B-frag: V[c*32+lg*8..][16df+lr]

  const float* bb = biasg + (size_t)h * N;
  unsigned short* Pw = P_lds[w];
  const int pbase = lr * 72;

  float m_old = -INFINITY, lsum = 0.f;
  const f32x4 zero4 = {0.f, 0.f, 0.f, 0.f};
  f32x4 oacc0 = zero4, oacc1 = zero4;

  // prologue: issue tile-0 staging loads
  bf16x8 kreg = *reinterpret_cast<const bf16x8*>(kgp + (size_t)(jlo + (tid >> 2)) * DD);
  bf16x8 vreg = *reinterpret_cast<const bf16x8*>(vgp + jlo);

  for (int j0 = jlo; j0 < jhi; j0 += 64) {
    // write staged regs (WAR-safe: barrier at end of prev iter)
    *reinterpret_cast<bf16x8*>(kls) = kreg;
    *reinterpret_cast<bf16x8*>(vls) = vreg;
    __syncthreads();   // K/V tile visible to all waves

    if (j0 + 64 < jhi) {   // T14: issue next tile's loads now, write next iter
      kreg = *reinterpret_cast<const bf16x8*>(kgp + (size_t)(j0 + 64 + (tid >> 2)) * DD);
      vreg = *reinterpret_cast<const bf16x8*>(vgp + j0 + 64);
    }

    // per-lane bias (log2 domain) for its 16 j values: j = jf*16 + lg*4 + r
    f32x4 bias4[4];
#pragma unroll
    for (int jf = 0; jf < 4; ++jf)
      bias4[jf] = *reinterpret_cast<const f32x4*>(bb + j0 + jf * 16 + lg * 4);

    // K frags from LDS (conflict-free)
    const bf16x8 kf0 = *reinterpret_cast<const bf16x8*>(kfb);
    const bf16x8 kf1 = *reinterpret_cast<const bf16x8*>(kfb + 128);
    const bf16x8 kf2 = *reinterpret_cast<const bf16x8*>(kfb + 256);
    const bf16x8 kf3 = *reinterpret_cast<const bf16x8*>(kfb + 384);

    f32x4 sc[4];
    __builtin_amdgcn_s_setprio(1);
    sc[0] = __builtin_amdgcn_mfma_f32_16x16x32_bf16(kf0, qf, zero4, 0, 0, 0);
    sc[1] = __builtin_amdgcn_mfma_f32_16x16x32_bf16(kf1, qf, zero4, 0, 0, 0);
    sc[2] = __builtin_amdgcn_mfma_f32_16x16x32_bf16(kf2, qf, zero4, 0, 0, 0);
    sc[3] = __builtin_amdgcn_mfma_f32_16x16x32_bf16(kf3, qf, zero4, 0, 0, 0);
    __builtin_amdgcn_s_setprio(0);

    // scale + bias (log2 domain), local max over this lane's 16 j values
    float p[4][4];
    float mloc = -INFINITY;
#pragma unroll
    for (int jf = 0; jf < 4; ++jf)
#pragma unroll
      for (int r = 0; r < 4; ++r) {
        float t = sc[jf][r] * scl2 + bias4[jf][r];
        p[jf][r] = t;
        mloc = fmaxf(mloc, t);
      }
    mloc = fmaxf(mloc, __shfl_xor(mloc, 16));
    mloc = fmaxf(mloc, __shfl_xor(mloc, 32));

    if (__any(mloc > m_old)) {   // exact defer: rescale only when max grows
      float m_new = fmaxf(m_old, mloc);
      float sf = __builtin_amdgcn_exp2f(m_old - m_new);
      m_old = m_new;
      lsum *= sf;
      float sf0 = __shfl(sf, lg * 4 + 0);
      float sf1 = __shfl(sf, lg * 4 + 1);
      float sf2 = __shfl(sf, lg * 4 + 2);
      float sf3 = __shfl(sf, lg * 4 + 3);
      oacc0[0] *= sf0; oacc0[1] *= sf1; oacc0[2] *= sf2; oacc0[3] *= sf3;
      oacc1[0] *= sf0; oacc1[1] *= sf1; oacc1[2] *= sf2; oacc1[3] *= sf3;
    }

    float rsum = 0.f;
#pragma unroll
    for (int jf = 0; jf < 4; ++jf) {
      float e0 = __builtin_amdgcn_exp2f(p[jf][0] - m_old);
      float e1 = __builtin_amdgcn_exp2f(p[jf][1] - m_old);
      float e2 = __builtin_amdgcn_exp2f(p[jf][2] - m_old);
      float e3 = __builtin_amdgcn_exp2f(p[jf][3] - m_old);
      rsum += (e0 + e1) + (e2 + e3);
      uint2 pk;
      pk.x = pack2(e0, e1);
      pk.y = pack2(e2, e3);
      // P[q=lr][j = jf*16 + lg*4 + r]
      *reinterpret_cast<uint2*>(Pw + pbase + jf * 16 + lg * 4) = pk;
    }
    rsum += __shfl_xor(rsum, 16);
    rsum += __shfl_xor(rsum, 32);
    lsum += rsum;

    // V frags from LDS (conflict-free)
    const bf16x8 v00 = *reinterpret_cast<const bf16x8*>(vfb);            // c0,df0
    const bf16x8 v01 = *reinterpret_cast<const bf16x8*>(vfb + 128);      // c0,df1
    const bf16x8 v10 = *reinterpret_cast<const bf16x8*>(vfb + 1024);     // c1,df0
    const bf16x8 v11 = *reinterpret_cast<const bf16x8*>(vfb + 1152);     // c1,df1

    // PV: O[16q][32d] += P[16q][64j] * V[64j][32d]
    const bf16x8 pf0 = *reinterpret_cast<const bf16x8*>(Pw + pbase + lg * 8);
    const bf16x8 pf1 = *reinterpret_cast<const bf16x8*>(Pw + pbase + 32 + lg * 8);
    __builtin_amdgcn_s_setprio(1);
    oacc0 = __builtin_amdgcn_mfma_f32_16x16x32_bf16(pf0, v00, oacc0, 0, 0, 0);
    oacc1 = __builtin_amdgcn_mfma_f32_16x16x32_bf16(pf0, v01, oacc1, 0, 0, 0);
    oacc0 = __builtin_amdgcn_mfma_f32_16x16x32_bf16(pf1, v10, oacc0, 0, 0, 0);
    oacc1 = __builtin_amdgcn_mfma_f32_16x16x32_bf16(pf1, v11, oacc1, 0, 0, 0);
    __builtin_amdgcn_s_setprio(0);

    __syncthreads();   // all waves done reading K/V tile before next overwrite
  }

  // stats for q = q0 + lr (identical in all lg groups; lg==0 stores)
  const size_t srow = ((size_t)s * NUM_H + h) * N;
  if (lg == 0) {
    mpart[srow + q0 + lr] = m_old;
    lpart[srow + q0 + lr] = lsum;
  }
  // unnormalized O: row q = lg*4 + r, cols d = lr and 16+lr
  float* Ob = Opart + (srow + q0) * 32;
#pragma unroll
  for (int r = 0; r < 4; ++r) {
    Ob[(size_t)(lg * 4 + r) * 32 + lr]      = oacc0[r];
    Ob[(size_t)(lg * 4 + r) * 32 + 16 + lr] = oacc1[r];
  }
}

// ---------------- combine split partials -> bf16 [N][256] -------------------
__global__ __launch_bounds__(256) void combine_kernel(const float* __restrict__ Op,
                                                      const float* __restrict__ mp,
                                                      const float* __restrict__ lp,
                                                      unsigned short* __restrict__ obf, int N) {
  const int idx = blockIdx.x * 256 + threadIdx.x;   // H*N*8 total
  const int d4 = idx & 7;
  const int row = idx >> 3;                         // row = h*N + n
  const size_t HN = (size_t)NUM_H * N;
  float m[NSPLIT], lv[NSPLIT];
#pragma unroll
  for (int s = 0; s < NSPLIT; ++s) {
    m[s]  = mp[s * HN + row];
    lv[s] = lp[s * HN + row];
  }
  float mmax = m[0];
#pragma unroll
  for (int s = 1; s < NSPLIT; ++s) mmax = fmaxf(mmax, m[s]);
  float wsum = 0.f, wgt[NSPLIT];
#pragma unroll
  for (int s = 0; s < NSPLIT; ++s) {
    wgt[s] = __builtin_amdgcn_exp2f(m[s] - mmax);
    wsum += lv[s] * wgt[s];
  }
  const float inv = 1.f / wsum;
  float4 acc = make_float4(0.f, 0.f, 0.f, 0.f);
#pragma unroll
  for (int s = 0; s < NSPLIT; ++s) {
    const float4 v = *reinterpret_cast<const float4*>(Op + (s * HN + row) * 32 + d4 * 4);
    acc.x += wgt[s] * v.x; acc.y += wgt[s] * v.y;
    acc.z += wgt[s] * v.z; acc.w += wgt[s] * v.w;
  }
  const int h = row / N, n = row - h * N;
  uint2 o;
  o.x = pack2(acc.x * inv, acc.y * inv);
  o.y = pack2(acc.z * inv, acc.w * inv);
  *reinterpret_cast<uint2*>(obf + (size_t)n * DD + h * HD + d4 * 4) = o;
}

// ---------------------------------------------------------------------------
extern "C" void kernel_launch(void* const* d_in, const int* in_sizes, int n_in,
                              void* d_out, int out_size, void* d_ws, size_t ws_size,
                              hipStream_t stream) {
  const float* x  = (const float*)d_in[0];
  const int* eidx = (const int*)d_in[1];
  const float* ea = (const float*)d_in[2];
  const float* Wq = (const float*)d_in[3];
  const float* bq = (const float*)d_in[4];
  const float* Wk = (const float*)d_in[5];
  const float* bk = (const float*)d_in[6];
  const float* Wv = (const float*)d_in[7];
  const float* bv = (const float*)d_in[8];
  const float* Wo = (const float*)d_in[9];
  const float* bo = (const float*)d_in[10];
  const float* We = (const float*)d_in[11];
  const float* be = (const float*)d_in[12];
  float* out = (float*)d_out;

  const int N = in_sizes[0] / DD;   // B=1
  const int E = in_sizes[1] / 2;
  const int* tgt = eidx + E;        // edge_index[1]

  // workspace layout
  unsigned short* xb  = (unsigned short*)d_ws;            // [N][256] bf16
  unsigned short* qbf = xb  + (size_t)N * DD;             // [N][256]
  unsigned short* kbf = qbf + (size_t)N * DD;             // [N][256]
  unsigned short* vT  = kbf + (size_t)N * DD;             // [256][N] transposed
  unsigned short* obf = vT  + (size_t)N * DD;             // [N][256]
  unsigned short* WTq = obf + (size_t)N * DD;             // [256][256] bf16 (W^T)
  unsigned short* WTk = WTq + DD * DD;
  unsigned short* WTv = WTk + DD * DD;
  unsigned short* WTo = WTv + DD * DD;
  float* bias  = (float*)(WTo + DD * DD);                 // [H][N] f32 (log2 dom.)
  float* Opart = bias + (size_t)NUM_H * N;                // [S][H][N][32] f32
  float* mpart = Opart + (size_t)NSPLIT * NUM_H * N * 32; // [S][H][N]
  float* lpart = mpart + (size_t)NSPLIT * NUM_H * N;      // [S][H][N]
  int*   sel   = (int*)(lpart + (size_t)NSPLIT * NUM_H * N); // [N]

  sel_init_kernel<<<(N + 255) / 256, 256, 0, stream>>>(sel, N);
  sel_scatter_kernel<<<(E + 255) / 256, 256, 0, stream>>>(tgt, sel, E);
  bias_build_kernel<<<(N + 255) / 256, 256, 0, stream>>>(sel, ea, We, be, bias, N);

  cvt_x_kernel<<<(N * DD) / 1024, 256, 0, stream>>>(x, xb);
  dim3 wg(8, 8, 4);
  cvt_wt_all<<<wg, 256, 0, stream>>>(Wq, Wk, Wv, Wo, WTq, WTk, WTv, WTo);

  dim3 pg(N / 64, DD / 32, 3);
  proj_qkv<<<pg, 256, 0, stream>>>(xb, WTq, WTk, WTv, bq, bk, bv, qbf, kbf, vT, N);

  // 1-D grid, head = bid&7 (XCD-clustered)
  attn_mfma<<<(N / 64) * NUM_H * NSPLIT, 256, 0, stream>>>(qbf, kbf, vT, bias,
                                                           Opart, mpart, lpart, N);

  combine_kernel<<<(NUM_H * N * 8) / 256, 256, 0, stream>>>(Opart, mpart, lpart, obf, N);

  dim3 og(N / 64, DD / 32);
  proj_out<<<og, 256, 0, stream>>>(obf, WTo, bo, out, N);
}

// Round 7
// 102.560 us; speedup vs baseline: 5.1118x; 1.1239x over previous
//
#include <hip/hip_runtime.h>
#include <hip/hip_bf16.h>
#include <math.h>

#define NUM_H 8
#define HD 32
#define DD 256
#define NSPLIT 2
#define KVBLK 128

typedef __attribute__((ext_vector_type(8))) short bf16x8;
typedef __attribute__((ext_vector_type(4))) float f32x4;

__device__ __forceinline__ unsigned short f2b(float f) {
  unsigned u = __builtin_bit_cast(unsigned, f);
  u += 0x7FFFu + ((u >> 16) & 1u);   // RNE
  return (unsigned short)(u >> 16);
}

__device__ __forceinline__ unsigned pack2(float a, float b) {
  float2 t; t.x = a; t.y = b;
  __hip_bfloat162 r = __float22bfloat162_rn(t);   // v_cvt_pk_bf16_f32
  unsigned u;
  __builtin_memcpy(&u, &r, sizeof(u));
  return u;
}

#define LOG2E 1.4426950408889634f

// ---------------- edge bias: last-write-wins scatter (numpy semantics) -----
__global__ void sel_init_kernel(int* __restrict__ sel, int N) {
  int t = blockIdx.x * 256 + threadIdx.x;
  if (t < N) sel[t] = -1;
}

__global__ void sel_scatter_kernel(const int* __restrict__ tgt, int* __restrict__ sel, int E) {
  int e = blockIdx.x * 256 + threadIdx.x;
  if (e < E) atomicMax(&sel[tgt[e]], e);   // max e == last occurrence wins
}

// stores bias * log2(e)  (softmax done in exp2 domain)
__global__ void bias_build_kernel(const int* __restrict__ sel, const float* __restrict__ ea,
                                  const float* __restrict__ We, const float* __restrict__ be,
                                  float* __restrict__ bias, int N) {
  int t = blockIdx.x * 256 + threadIdx.x;
  if (t >= N) return;
  int e = sel[t];
  bool has = (e >= 0);
  float a0 = 0.f, a1 = 0.f, a2 = 0.f;
  if (has) {
    a0 = ea[3 * (size_t)e];
    a1 = ea[3 * (size_t)e + 1];
    a2 = ea[3 * (size_t)e + 2];
  }
#pragma unroll
  for (int h = 0; h < NUM_H; ++h) {
    float v = has ? (a0 * We[h] + a1 * We[NUM_H + h] + a2 * We[2 * NUM_H + h] + be[h]) : 0.f;
    bias[(size_t)h * N + t] = v * LOG2E;   // [H][N]
  }
}

// ---------------- fp32 -> bf16 converts ------------------------------------
__global__ void cvt_x_kernel(const float* __restrict__ x, unsigned short* __restrict__ xb) {
  int i = blockIdx.x * 256 + threadIdx.x;   // 4 elems per thread
  const float4 v = *reinterpret_cast<const float4*>(x + (size_t)i * 4);
  uint2 o;
  o.x = pack2(v.x, v.y);
  o.y = pack2(v.z, v.w);
  *reinterpret_cast<uint2*>(xb + (size_t)i * 4) = o;
}

// WT[c][k] = bf16(W[k][c]) for 4 weights, LDS tile transpose. z picks the matrix.
__global__ void cvt_wt_all(const float* __restrict__ W0, const float* __restrict__ W1,
                           const float* __restrict__ W2, const float* __restrict__ W3,
                           unsigned short* __restrict__ T0, unsigned short* __restrict__ T1,
                           unsigned short* __restrict__ T2, unsigned short* __restrict__ T3) {
  __shared__ float t[32][33];
  const int z = blockIdx.z;
  const float* W = (z == 0) ? W0 : (z == 1) ? W1 : (z == 2) ? W2 : W3;
  unsigned short* WT = (z == 0) ? T0 : (z == 1) ? T1 : (z == 2) ? T2 : T3;
  const int bx = blockIdx.x, by = blockIdx.y;
  const int lx = threadIdx.x & 31, ly = threadIdx.x >> 5;   // 256 thr: ly 0..7
#pragma unroll
  for (int r = 0; r < 32; r += 8)
    t[r + ly][lx] = W[(size_t)(bx * 32 + r + ly) * DD + by * 32 + lx];
  __syncthreads();
#pragma unroll
  for (int r = 0; r < 32; r += 8)
    WT[(size_t)(by * 32 + r + ly) * DD + bx * 32 + lx] = f2b(t[lx][r + ly]);
}

// ---------------- MFMA projection core -------------------------------------
__device__ __forceinline__ void proj_core(const unsigned short* __restrict__ Xb,
                                          const unsigned short* __restrict__ WT,
                                          int n0, int c0, int lr, int lg,
                                          f32x4& acc0, f32x4& acc1) {
  const f32x4 zero4 = {0.f, 0.f, 0.f, 0.f};
  acc0 = zero4; acc1 = zero4;
  const unsigned short* ap  = Xb + (size_t)(n0 + lr) * DD + lg * 8;
  const unsigned short* bp0 = WT + (size_t)(c0 + lr) * DD + lg * 8;
  const unsigned short* bp1 = bp0 + 16 * DD;
#pragma unroll
  for (int kk = 0; kk < 8; ++kk) {
    bf16x8 a  = *reinterpret_cast<const bf16x8*>(ap + kk * 32);
    bf16x8 b0 = *reinterpret_cast<const bf16x8*>(bp0 + kk * 32);
    bf16x8 b1 = *reinterpret_cast<const bf16x8*>(bp1 + kk * 32);
    acc0 = __builtin_amdgcn_mfma_f32_16x16x32_bf16(a, b0, acc0, 0, 0, 0);
    acc1 = __builtin_amdgcn_mfma_f32_16x16x32_bf16(a, b1, acc1, 0, 0, 0);
  }
}

// fused Q/K/V projection; z = 0:Q, 1:K (bf16 [N][256]), 2:V (bf16 T [256][N])
__global__ __launch_bounds__(256) void proj_qkv(const unsigned short* __restrict__ Xb,
                                                const unsigned short* __restrict__ WTq,
                                                const unsigned short* __restrict__ WTk,
                                                const unsigned short* __restrict__ WTv,
                                                const float* __restrict__ bq,
                                                const float* __restrict__ bk,
                                                const float* __restrict__ bv,
                                                unsigned short* __restrict__ qbf,
                                                unsigned short* __restrict__ kbf,
                                                unsigned short* __restrict__ vT, int N) {
  const int z = blockIdx.z;
  const unsigned short* WT = (z == 0) ? WTq : (z == 1) ? WTk : WTv;
  const float* bias = (z == 0) ? bq : (z == 1) ? bk : bv;
  const int w = threadIdx.x >> 6, l = threadIdx.x & 63;
  const int lr = l & 15, lg = l >> 4;
  const int n0 = (blockIdx.x * 4 + w) * 16;
  const int c0 = blockIdx.y * 32;
  f32x4 acc0, acc1;
  proj_core(Xb, WT, n0, c0, lr, lg, acc0, acc1);
  const float bc0 = bias[c0 + lr], bc1 = bias[c0 + 16 + lr];
  if (z < 2) {
    unsigned short* Yb = z ? kbf : qbf;
#pragma unroll
    for (int r = 0; r < 4; ++r) {
      Yb[(size_t)(n0 + lg * 4 + r) * DD + c0 + lr]      = f2b(acc0[r] + bc0);
      Yb[(size_t)(n0 + lg * 4 + r) * DD + c0 + 16 + lr] = f2b(acc1[r] + bc1);
    }
  } else {
    uint2 o0, o1;
    o0.x = pack2(acc0[0] + bc0, acc0[1] + bc0);
    o0.y = pack2(acc0[2] + bc0, acc0[3] + bc0);
    o1.x = pack2(acc1[0] + bc1, acc1[1] + bc1);
    o1.y = pack2(acc1[2] + bc1, acc1[3] + bc1);
    *reinterpret_cast<uint2*>(vT + (size_t)(c0 + lr) * N + n0 + lg * 4)      = o0;
    *reinterpret_cast<uint2*>(vT + (size_t)(c0 + 16 + lr) * N + n0 + lg * 4) = o1;
  }
}

// output projection: f32 out
__global__ __launch_bounds__(256) void proj_out(const unsigned short* __restrict__ Xb,
                                                const unsigned short* __restrict__ WT,
                                                const float* __restrict__ bias,
                                                float* __restrict__ Y, int N) {
  const int w = threadIdx.x >> 6, l = threadIdx.x & 63;
  const int lr = l & 15, lg = l >> 4;
  const int n0 = (blockIdx.x * 4 + w) * 16;
  const int c0 = blockIdx.y * 32;
  f32x4 acc0, acc1;
  proj_core(Xb, WT, n0, c0, lr, lg, acc0, acc1);
  const float bc0 = bias[c0 + lr], bc1 = bias[c0 + 16 + lr];
#pragma unroll
  for (int r = 0; r < 4; ++r) {
    Y[(size_t)(n0 + lg * 4 + r) * DD + c0 + lr]      = acc0[r] + bc0;
    Y[(size_t)(n0 + lg * 4 + r) * DD + c0 + 16 + lr] = acc1[r] + bc1;
  }
}

// ---------------- flash attention, bf16 MFMA, KVBLK=128, swizzled LDS -------
// 1-D grid (N/64)*H*NSPLIT, h = bid&7 (XCD-clustered).
// R7: (a) XOR-swizzled K/V staging (write conflicts 4/8-way -> <=2-way free),
//     (b) KVBLK 128 (half the barriers, 8-MFMA clusters per phase),
//     (c) NSPLIT 2 (half the Opart f32 traffic; 4 blocks/CU exactly).
// K LDS:  Ks[kg:4][j^(kg*2):128][8]   (kg = k-chunk of 8)
// V LDS:  Vs[js:16][d^(js&7):32][8]   (js = j-chunk of 8)
// P LDS:  per-wave [16 q][128 j], row stride 136 shorts.
__global__ __launch_bounds__(256, 4) void attn_mfma(const unsigned short* __restrict__ qb,
                                                    const unsigned short* __restrict__ kb,
                                                    const unsigned short* __restrict__ vT,
                                                    const float* __restrict__ biasg,
                                                    float* __restrict__ Opart,
                                                    float* __restrict__ mpart,
                                                    float* __restrict__ lpart, int N) {
  __shared__ unsigned short Ks[4 * 128 * 8];       // 8 KB
  __shared__ unsigned short Vs[16 * 32 * 8];       // 8 KB
  __shared__ unsigned short P_lds[4][16 * 136];    // 17 KB
  const int tid = threadIdx.x;
  const int w = tid >> 6, l = tid & 63;
  const int lr = l & 15, lg = l >> 4;
  const int bid = blockIdx.x;
  const int h = bid & 7;                 // XCD-clustered head
  const int rem = bid >> 3;
  const int qblk = rem & 63;
  const int s = rem >> 6;
  const int q0 = qblk * 64 + w * 16;
  const int hk = h * HD;
  const int jlo = s * (N / NSPLIT), jhi = jlo + N / NSPLIT;
  const float scl2 = 0.17677669529663687f * LOG2E;   // 1/sqrt(32) * log2(e)

  const bf16x8 qf = *reinterpret_cast<const bf16x8*>(qb + (size_t)(q0 + lr) * DD + hk + lg * 8);

  // staging: K: thread t -> (kg=t&3, j=t>>2) and (kg, j+64); coalesced 64B groups
  //          V: thread t -> (js=t&7, d=t>>3) and (js+8, d); coalesced 128B rows
  const unsigned short* kgp = kb + hk + (tid & 3) * 8;
  const unsigned short* vgp = vT + (size_t)(hk + (tid >> 3)) * N + (tid & 7) * 8;
  unsigned short* kls0 = Ks + (tid & 3) * 1024 + (((tid >> 2) ^ ((tid & 3) << 1))) * 8;
  unsigned short* kls1 = kls0 + 512;     // j+64: (j+64)^sw = (j^sw)+64
  unsigned short* vls0 = Vs + (tid & 7) * 256 + (((tid >> 3) ^ (tid & 7))) * 8;
  unsigned short* vls1 = vls0 + 2048;    // js+8: same XOR (js&7 unchanged)
  // frag-read bases (loop-invariant, conflict-free after swizzle)
  const unsigned short* kfb  = Ks + lg * 1024 + (lr ^ (lg << 1)) * 8;
  const unsigned short* vfb0 = Vs + lg * 256 + (lr ^ lg) * 8;              // js=lg (+c/2*8js)
  const unsigned short* vfb1 = Vs + (lg + 4) * 256 + (lr ^ (lg + 4)) * 8;  // js=lg+4

  const float* bb = biasg + (size_t)h * N;
  unsigned short* Pw = P_lds[w];
  const int pbase = lr * 136;

  float m_old = -INFINITY, lsum = 0.f;
  const f32x4 zero4 = {0.f, 0.f, 0.f, 0.f};
  f32x4 oacc0 = zero4, oacc1 = zero4;

  // prologue: issue tile-0 staging loads
  int krow = jlo + (tid >> 2);
  bf16x8 kreg0 = *reinterpret_cast<const bf16x8*>(kgp + (size_t)krow * DD);
  bf16x8 kreg1 = *reinterpret_cast<const bf16x8*>(kgp + (size_t)(krow + 64) * DD);
  bf16x8 vreg0 = *reinterpret_cast<const bf16x8*>(vgp + jlo);
  bf16x8 vreg1 = *reinterpret_cast<const bf16x8*>(vgp + jlo + 64);

  for (int j0 = jlo; j0 < jhi; j0 += KVBLK) {
    *reinterpret_cast<bf16x8*>(kls0) = kreg0;
    *reinterpret_cast<bf16x8*>(kls1) = kreg1;
    *reinterpret_cast<bf16x8*>(vls0) = vreg0;
    *reinterpret_cast<bf16x8*>(vls1) = vreg1;
    __syncthreads();   // K/V tile visible to all waves

    if (j0 + KVBLK < jhi) {   // T14: issue next tile's loads now, write next iter
      krow += KVBLK;
      kreg0 = *reinterpret_cast<const bf16x8*>(kgp + (size_t)krow * DD);
      kreg1 = *reinterpret_cast<const bf16x8*>(kgp + (size_t)(krow + 64) * DD);
      vreg0 = *reinterpret_cast<const bf16x8*>(vgp + j0 + KVBLK);
      vreg1 = *reinterpret_cast<const bf16x8*>(vgp + j0 + KVBLK + 64);
    }

    // ---- QK^T: 8 MFMA over 128 j
    f32x4 sc[8];
    __builtin_amdgcn_s_setprio(1);
#pragma unroll
    for (int jf = 0; jf < 8; ++jf) {
      const bf16x8 kf = *reinterpret_cast<const bf16x8*>(kfb + jf * 128);
      sc[jf] = __builtin_amdgcn_mfma_f32_16x16x32_bf16(kf, qf, zero4, 0, 0, 0);
    }
    __builtin_amdgcn_s_setprio(0);

    // ---- softmax (log2 domain) over this lane's 32 j values
    float p[8][4];
    float mloc = -INFINITY;
#pragma unroll
    for (int jf = 0; jf < 8; ++jf) {
      const f32x4 b4 = *reinterpret_cast<const f32x4*>(bb + j0 + jf * 16 + lg * 4);
#pragma unroll
      for (int r = 0; r < 4; ++r) {
        float t = sc[jf][r] * scl2 + b4[r];
        p[jf][r] = t;
        mloc = fmaxf(mloc, t);
      }
    }
    mloc = fmaxf(mloc, __shfl_xor(mloc, 16));
    mloc = fmaxf(mloc, __shfl_xor(mloc, 32));

    if (__any(mloc > m_old)) {   // exact defer: rescale only when max grows
      float m_new = fmaxf(m_old, mloc);
      float sf = __builtin_amdgcn_exp2f(m_old - m_new);
      m_old = m_new;
      lsum *= sf;
      float sf0 = __shfl(sf, lg * 4 + 0);
      float sf1 = __shfl(sf, lg * 4 + 1);
      float sf2 = __shfl(sf, lg * 4 + 2);
      float sf3 = __shfl(sf, lg * 4 + 3);
      oacc0[0] *= sf0; oacc0[1] *= sf1; oacc0[2] *= sf2; oacc0[3] *= sf3;
      oacc1[0] *= sf0; oacc1[1] *= sf1; oacc1[2] *= sf2; oacc1[3] *= sf3;
    }

    float rsum = 0.f;
#pragma unroll
    for (int jf = 0; jf < 8; ++jf) {
      float e0 = __builtin_amdgcn_exp2f(p[jf][0] - m_old);
      float e1 = __builtin_amdgcn_exp2f(p[jf][1] - m_old);
      float e2 = __builtin_amdgcn_exp2f(p[jf][2] - m_old);
      float e3 = __builtin_amdgcn_exp2f(p[jf][3] - m_old);
      rsum += (e0 + e1) + (e2 + e3);
      uint2 pk;
      pk.x = pack2(e0, e1);
      pk.y = pack2(e2, e3);
      *reinterpret_cast<uint2*>(Pw + pbase + jf * 16 + lg * 4) = pk;   // P[q=lr][j]
    }
    rsum += __shfl_xor(rsum, 16);
    rsum += __shfl_xor(rsum, 32);
    lsum += rsum;

    // ---- PV: 4 j-chunks x 2 d-halves, 8 MFMA
    __builtin_amdgcn_s_setprio(1);
#pragma unroll
    for (int c = 0; c < 4; ++c) {
      const bf16x8 pf = *reinterpret_cast<const bf16x8*>(Pw + pbase + c * 32 + lg * 8);
      const unsigned short* vb = ((c & 1) ? vfb1 : vfb0) + (c >> 1) * 2048;
      const bf16x8 v0 = *reinterpret_cast<const bf16x8*>(vb);
      const bf16x8 v1 = *reinterpret_cast<const bf16x8*>(vb + 128);
      oacc0 = __builtin_amdgcn_mfma_f32_16x16x32_bf16(pf, v0, oacc0, 0, 0, 0);
      oacc1 = __builtin_amdgcn_mfma_f32_16x16x32_bf16(pf, v1, oacc1, 0, 0, 0);
    }
    __builtin_amdgcn_s_setprio(0);

    __syncthreads();   // all waves done reading K/V before next overwrite
  }

  // stats for q = q0 + lr (identical in all lg groups; lg==0 stores)
  const size_t srow = ((size_t)s * NUM_H + h) * N;
  if (lg == 0) {
    mpart[srow + q0 + lr] = m_old;
    lpart[srow + q0 + lr] = lsum;
  }
  // unnormalized O: row q = lg*4 + r, cols d = lr and 16+lr
  float* Ob = Opart + (srow + q0) * 32;
#pragma unroll
  for (int r = 0; r < 4; ++r) {
    Ob[(size_t)(lg * 4 + r) * 32 + lr]      = oacc0[r];
    Ob[(size_t)(lg * 4 + r) * 32 + 16 + lr] = oacc1[r];
  }
}

// ---------------- combine split partials -> bf16 [N][256] -------------------
__global__ __launch_bounds__(256) void combine_kernel(const float* __restrict__ Op,
                                                      const float* __restrict__ mp,
                                                      const float* __restrict__ lp,
                                                      unsigned short* __restrict__ obf, int N) {
  const int idx = blockIdx.x * 256 + threadIdx.x;   // H*N*8 total
  const int d4 = idx & 7;
  const int row = idx >> 3;                         // row = h*N + n
  const size_t HN = (size_t)NUM_H * N;
  float m[NSPLIT], lv[NSPLIT];
#pragma unroll
  for (int s = 0; s < NSPLIT; ++s) {
    m[s]  = mp[s * HN + row];
    lv[s] = lp[s * HN + row];
  }
  float mmax = m[0];
#pragma unroll
  for (int s = 1; s < NSPLIT; ++s) mmax = fmaxf(mmax, m[s]);
  float wsum = 0.f, wgt[NSPLIT];
#pragma unroll
  for (int s = 0; s < NSPLIT; ++s) {
    wgt[s] = __builtin_amdgcn_exp2f(m[s] - mmax);
    wsum += lv[s] * wgt[s];
  }
  const float inv = 1.f / wsum;
  float4 acc = make_float4(0.f, 0.f, 0.f, 0.f);
#pragma unroll
  for (int s = 0; s < NSPLIT; ++s) {
    const float4 v = *reinterpret_cast<const float4*>(Op + (s * HN + row) * 32 + d4 * 4);
    acc.x += wgt[s] * v.x; acc.y += wgt[s] * v.y;
    acc.z += wgt[s] * v.z; acc.w += wgt[s] * v.w;
  }
  const int h = row / N, n = row - h * N;
  uint2 o;
  o.x = pack2(acc.x * inv, acc.y * inv);
  o.y = pack2(acc.z * inv, acc.w * inv);
  *reinterpret_cast<uint2*>(obf + (size_t)n * DD + h * HD + d4 * 4) = o;
}

// ---------------------------------------------------------------------------
extern "C" void kernel_launch(void* const* d_in, const int* in_sizes, int n_in,
                              void* d_out, int out_size, void* d_ws, size_t ws_size,
                              hipStream_t stream) {
  const float* x  = (const float*)d_in[0];
  const int* eidx = (const int*)d_in[1];
  const float* ea = (const float*)d_in[2];
  const float* Wq = (const float*)d_in[3];
  const float* bq = (const float*)d_in[4];
  const float* Wk = (const float*)d_in[5];
  const float* bk = (const float*)d_in[6];
  const float* Wv = (const float*)d_in[7];
  const float* bv = (const float*)d_in[8];
  const float* Wo = (const float*)d_in[9];
  const float* bo = (const float*)d_in[10];
  const float* We = (const float*)d_in[11];
  const float* be = (const float*)d_in[12];
  float* out = (float*)d_out;

  const int N = in_sizes[0] / DD;   // B=1
  const int E = in_sizes[1] / 2;
  const int* tgt = eidx + E;        // edge_index[1]

  // workspace layout
  unsigned short* xb  = (unsigned short*)d_ws;            // [N][256] bf16
  unsigned short* qbf = xb  + (size_t)N * DD;             // [N][256]
  unsigned short* kbf = qbf + (size_t)N * DD;             // [N][256]
  unsigned short* vT  = kbf + (size_t)N * DD;             // [256][N] transposed
  unsigned short* obf = vT  + (size_t)N * DD;             // [N][256]
  unsigned short* WTq = obf + (size_t)N * DD;             // [256][256] bf16 (W^T)
  unsigned short* WTk = WTq + DD * DD;
  unsigned short* WTv = WTk + DD * DD;
  unsigned short* WTo = WTv + DD * DD;
  float* bias  = (float*)(WTo + DD * DD);                 // [H][N] f32 (log2 dom.)
  float* Opart = bias + (size_t)NUM_H * N;                // [S][H][N][32] f32
  float* mpart = Opart + (size_t)NSPLIT * NUM_H * N * 32; // [S][H][N]
  float* lpart = mpart + (size_t)NSPLIT * NUM_H * N;      // [S][H][N]
  int*   sel   = (int*)(lpart + (size_t)NSPLIT * NUM_H * N); // [N]

  sel_init_kernel<<<(N + 255) / 256, 256, 0, stream>>>(sel, N);
  sel_scatter_kernel<<<(E + 255) / 256, 256, 0, stream>>>(tgt, sel, E);
  bias_build_kernel<<<(N + 255) / 256, 256, 0, stream>>>(sel, ea, We, be, bias, N);

  cvt_x_kernel<<<(N * DD) / 1024, 256, 0, stream>>>(x, xb);
  dim3 wg(8, 8, 4);
  cvt_wt_all<<<wg, 256, 0, stream>>>(Wq, Wk, Wv, Wo, WTq, WTk, WTv, WTo);

  dim3 pg(N / 64, DD / 32, 3);
  proj_qkv<<<pg, 256, 0, stream>>>(xb, WTq, WTk, WTv, bq, bk, bv, qbf, kbf, vT, N);

  // 1-D grid, head = bid&7 (XCD-clustered)
  attn_mfma<<<(N / 64) * NUM_H * NSPLIT, 256, 0, stream>>>(qbf, kbf, vT, bias,
                                                           Opart, mpart, lpart, N);

  combine_kernel<<<(NUM_H * N * 8) / 256, 256, 0, stream>>>(Opart, mpart, lpart, obf, N);

  dim3 og(N / 64, DD / 32);
  proj_out<<<og, 256, 0, stream>>>(obf, WTo, bo, out, N);
}